// Round 7
// baseline (1204.612 us; speedup 1.0000x reference)
//
#include <hip/hip_runtime.h>
#include <stdint.h>

// ---------------- problem constants ----------------
#define K_H    8
#define K_D    64
#define K_G    64
#define K_DIM  256
#define K_INNER 512
#define K_B    4
#define K_N    32768

// ---------------- LDS layout ----------------
#define XS          264                   // x tile row stride (bf16 elems), 528B, 16B aligned
#define XLDS_BYTES  (64 * XS * 2)         // 33792
#define BUFA_STR    72                    // 144B rows, 16B aligned
#define BUFA_BYTES  (64 * BUFA_STR * 2)   // 9216
#define BUF2_STR    40                    // 80B rows, 16B aligned
#define BUF2_BYTES  (64 * BUF2_STR * 2)   // 5120
#define P1_WAVE_BYTES (BUFA_BYTES + BUF2_BYTES)         // 14336
#define P1_LDS      (XLDS_BYTES + 8 * P1_WAVE_BYTES)    // 148480  (<=160K) -> 1 block/CU
#define OX_STR      520                   // 1040B rows, 16B aligned
#define OX_BYTES    (64 * OX_STR * 2)     // 66560
#define P3_LDS      (XLDS_BYTES + 8 * BUF2_BYTES + OX_BYTES)  // 141312 -> 1 block/CU
#define P2_LDS      (5 * 64 * 65 * 4 + 2 * 64 * 4)      // 83712

// ---------------- workspace layout (bytes) — identical to verified baseline ----------------
#define WFX_OFF   0
#define WX_OFF    (512 * 256 * 2)         // holds Weff = Wsl·Wx (bf16, same shape as Wx)
#define WOUT_OFF  (WX_OFF + 512 * 256 * 2)
#define WSL_OFF   (WOUT_OFF + 256 * 512 * 2)  // holds beff = Wsl·bx + bsl (fp32, 512 floats)
#define STN_OFF   (WSL_OFF + 64 * 64 * 2)
#define SNORM_OFF (STN_OFF + 4 * 8 * 64 * 64 * 4)
#define OST_OFF   (SNORM_OFF + 4 * 8 * 64 * 4)
// total = OST_OFF + 4*8*64*64*2 = ~1.6 MB (same as baseline)

// partial accumulators live in d_out (128 MiB; pass3 fully overwrites it later):
#define PART_ST_FLOATS (256 * 8 * 4096)   // 8388608

typedef __attribute__((ext_vector_type(8))) short short8;  // 8 x bf16 (4 VGPRs)
typedef __attribute__((ext_vector_type(4))) float f4;      // MFMA C/D frag; also nt-load vehicle
typedef __attribute__((ext_vector_type(4))) unsigned short us4;

static __device__ __forceinline__ f4 MFMA(short8 a, short8 b, f4 c) {
  return __builtin_amdgcn_mfma_f32_16x16x32_bf16(a, b, c, 0, 0, 0);
}
static __device__ __forceinline__ unsigned short f2bf(float f) {
  union { float f; unsigned u; } v; v.f = f;
  unsigned r = v.u + 0x7FFFu + ((v.u >> 16) & 1u);  // RNE
  return (unsigned short)(r >> 16);
}
static __device__ __forceinline__ us4 pack4(f4 v) {
  us4 p; p[0] = f2bf(v[0]); p[1] = f2bf(v[1]); p[2] = f2bf(v[2]); p[3] = f2bf(v[3]);
  return p;
}
// stage one 64x256 fp32 tile -> bf16 LDS [64][XS] (pass3 one-shot staging)
static __device__ __forceinline__ void stage_x(const float* __restrict__ xp,
                                               unsigned short* xlds, int tid) {
#pragma unroll
  for (int j = 0; j < 8; ++j) {
    int fi = j * 2048 + tid * 4;
    f4 v = __builtin_nontemporal_load((const f4*)(xp + fi));
    int row = fi >> 8, col = fi & 255;
    us4 p; p[0] = f2bf(v[0]); p[1] = f2bf(v[1]); p[2] = f2bf(v[2]); p[3] = f2bf(v[3]);
    *(us4*)(xlds + row * XS + col) = p;
  }
}

// ---------------- prep: weights->bf16, Weff = Wsl·Wx, beff = Wsl·bx + bsl ----------------
__global__ void prep_kernel(const float* __restrict__ Wfx, const float* __restrict__ Wx,
                            const float* __restrict__ Wsl, const float* __restrict__ Wout,
                            const float* __restrict__ bx, const float* __restrict__ bsl,
                            char* __restrict__ ws) {
  int idx = blockIdx.x * blockDim.x + threadIdx.x;
  int stride = gridDim.x * blockDim.x;
  unsigned short* wfxb  = (unsigned short*)(ws + WFX_OFF);
  unsigned short* weffb = (unsigned short*)(ws + WX_OFF);
  unsigned short* woutb = (unsigned short*)(ws + WOUT_OFF);
  float* beff = (float*)(ws + WSL_OFF);
  for (int i = idx; i < 512 * 256; i += stride) wfxb[i] = f2bf(Wfx[i]);
  for (int i = idx; i < 256 * 512; i += stride) woutb[i] = f2bf(Wout[i]);
  // Weff[h][g][k] = sum_d Wsl[g][d] * Wx[h*64+d][k]   (fp32 accumulate, one bf16 round)
  for (int i = idx; i < 8 * 64 * 256; i += stride) {
    int k = i & 255, g = (i >> 8) & 63, hh = i >> 14;
    float s = 0.f;
#pragma unroll 8
    for (int d = 0; d < 64; ++d) s += Wsl[g * 64 + d] * Wx[(size_t)(hh * 64 + d) * 256 + k];
    weffb[i] = f2bf(s);
  }
  // beff[h][g] = sum_d Wsl[g][d] * bx[h*64+d] + bsl[g]
  for (int i = idx; i < 8 * 64; i += stride) {
    int g = i & 63, hh = i >> 6;
    float s = bsl[g];
    for (int d = 0; d < 64; ++d) s += Wsl[g * 64 + d] * bx[hh * 64 + d];
    beff[i] = s;
  }
}

// ---------------- pass1: proj + softmax + pool (persistent, wave = head) ----------------
// Weff collapse: logits = Weff·x directly from the x LDS tile (xm never materialized).
// x tile t+1 is prefetched into registers while tile t computes (hides HBM latency).
// __launch_bounds__(512, 1): LDS (148 KB) already limits to 1 block/CU; the (512,2)
// variant capped VGPRs at 128 and spilled the prefetch regs to scratch
// (round-6 counters: WRITE_SIZE 285->846 MB = spill signature).
__launch_bounds__(512, 1)
__global__ void pass1_kernel(const float* __restrict__ x,
                             const unsigned short* __restrict__ wfx,
                             const unsigned short* __restrict__ weff,
                             const float* __restrict__ beff,
                             const float* __restrict__ bfx,
                             const float* __restrict__ temp,
                             float* __restrict__ part_st,
                             float* __restrict__ part_sn) {
  extern __shared__ char lds[];
  const int tid = threadIdx.x;
  const int lane = tid & 63;
  const int h = tid >> 6;          // wave id == head
  const int l15 = lane & 15;
  const int q = lane >> 4;
  const int b = blockIdx.x >> 6;   // 64 blocks per batch
  const int blb = blockIdx.x & 63;

  unsigned short* xlds = (unsigned short*)lds;
  unsigned short* bufA = (unsigned short*)(lds + XLDS_BYTES + h * P1_WAVE_BYTES);
  unsigned short* buf2 = bufA + BUFA_BYTES / 2;

  const float inv_t = 1.0f / temp[h];
  float bfx_v[4];
#pragma unroll
  for (int ci = 0; ci < 4; ++ci) bfx_v[ci] = bfx[h * 64 + 16 * ci + l15];
  f4 botg[4];
#pragma unroll
  for (int gi = 0; gi < 4; ++gi)
#pragma unroll
    for (int r = 0; r < 4; ++r) botg[gi][r] = beff[h * 64 + 16 * gi + 4 * q + r] * inv_t;

  const f4 fz = {0.f, 0.f, 0.f, 0.f};
  f4 stacc[4][4];   // st[g][c] accumulator, persistent over the 8 tiles
  f4 snacc[4];      // snorm partial per lane
#pragma unroll
  for (int i = 0; i < 4; ++i) {
    snacc[i] = fz;
#pragma unroll
    for (int j = 0; j < 4; ++j) stacc[i][j] = fz;
  }

  const float* xbase = x + ((size_t)b * K_N + blb * 512) * K_DIM;
  f4 xreg[8];
#pragma unroll
  for (int j = 0; j < 8; ++j)
    xreg[j] = __builtin_nontemporal_load((const f4*)(xbase + j * 2048 + tid * 4));

  for (int t = 0; t < 8; ++t) {
    __syncthreads();
    // write prefetched tile into LDS (bf16)
#pragma unroll
    for (int j = 0; j < 8; ++j) {
      int fi = j * 2048 + tid * 4;
      int row = fi >> 8, col = fi & 255;
      us4 p; p[0] = f2bf(xreg[j][0]); p[1] = f2bf(xreg[j][1]);
      p[2] = f2bf(xreg[j][2]); p[3] = f2bf(xreg[j][3]);
      *(us4*)(xlds + row * XS + col) = p;
    }
    __syncthreads();
    // issue next tile's loads now; they complete during this tile's compute
    if (t < 7) {
      const float* xp2 = xbase + (size_t)(t + 1) * 16384;
#pragma unroll
      for (int j = 0; j < 8; ++j)
        xreg[j] = __builtin_nontemporal_load((const f4*)(xp2 + j * 2048 + tid * 4));
    }

    // ---- logits GEMM (direct): D[g][n] = sum_k Weff[g][k] * x[n][k] ----
    f4 accL[4][4];
#pragma unroll
    for (int i = 0; i < 4; ++i)
#pragma unroll
      for (int j = 0; j < 4; ++j) accL[i][j] = fz;
#pragma unroll
    for (int ks = 0; ks < 8; ++ks) {
      short8 xb[4], wl[4];
#pragma unroll
      for (int ni = 0; ni < 4; ++ni)
        xb[ni] = *(const short8*)(xlds + (16 * ni + l15) * XS + 32 * ks + 8 * q);
#pragma unroll
      for (int gi = 0; gi < 4; ++gi)
        wl[gi] = *(const short8*)(weff + (size_t)(h * 64 + 16 * gi + l15) * K_DIM + 32 * ks + 8 * q);
#pragma unroll
      for (int gi = 0; gi < 4; ++gi)
#pragma unroll
        for (int ni = 0; ni < 4; ++ni)
          accL[gi][ni] = MFMA(wl[gi], xb[ni], accL[gi][ni]);
    }
#pragma unroll
    for (int gi = 0; gi < 4; ++gi)
#pragma unroll
      for (int ni = 0; ni < 4; ++ni)
        accL[gi][ni] = accL[gi][ni] * inv_t + botg[gi];

    // ---- softmax over g (rows): in-lane over 16 regs + shuffle over quads ----
    unsigned swp[4][4][2];
#pragma unroll
    for (int ni = 0; ni < 4; ++ni) {
      float m = -3.0e38f;
#pragma unroll
      for (int gi = 0; gi < 4; ++gi)
#pragma unroll
        for (int r = 0; r < 4; ++r) m = fmaxf(m, accL[gi][ni][r]);
      m = fmaxf(m, __shfl_xor(m, 16));
      m = fmaxf(m, __shfl_xor(m, 32));
      float s = 0.f;
#pragma unroll
      for (int gi = 0; gi < 4; ++gi) {
        f4 e;
#pragma unroll
        for (int r = 0; r < 4; ++r) e[r] = __expf(accL[gi][ni][r] - m);
        accL[gi][ni] = e;
        s += e[0] + e[1] + e[2] + e[3];
      }
      s += __shfl_xor(s, 16);
      s += __shfl_xor(s, 32);
      const float rinv = 1.0f / s;
#pragma unroll
      for (int gi = 0; gi < 4; ++gi) {
        accL[gi][ni] *= rinv;
        snacc[gi] += accL[gi][ni];
        swp[gi][ni][0] = (unsigned)f2bf(accL[gi][ni][0]) | ((unsigned)f2bf(accL[gi][ni][1]) << 16);
        swp[gi][ni][1] = (unsigned)f2bf(accL[gi][ni][2]) | ((unsigned)f2bf(accL[gi][ni][3]) << 16);
      }
    }

    // ---- fx GEMM: D[n][c] = sum_k x[n][k] * Wfx[c][k] ----
    f4 accF[4][4];
#pragma unroll
    for (int i = 0; i < 4; ++i)
#pragma unroll
      for (int j = 0; j < 4; ++j) accF[i][j] = fz;
#pragma unroll
    for (int ks = 0; ks < 8; ++ks) {
      short8 xa[4], wb[4];
#pragma unroll
      for (int mi = 0; mi < 4; ++mi)
        xa[mi] = *(const short8*)(xlds + (16 * mi + l15) * XS + 32 * ks + 8 * q);
#pragma unroll
      for (int ci = 0; ci < 4; ++ci)
        wb[ci] = *(const short8*)(wfx + (size_t)(h * 64 + 16 * ci + l15) * K_DIM + 32 * ks + 8 * q);
#pragma unroll
      for (int mi = 0; mi < 4; ++mi)
#pragma unroll
        for (int ci = 0; ci < 4; ++ci)
          accF[mi][ci] = MFMA(xa[mi], wb[ci], accF[mi][ci]);
    }
    // flush fx^T[c][n] into bufA (fast quad writes along n)
#pragma unroll
    for (int mi = 0; mi < 4; ++mi)
#pragma unroll
      for (int ci = 0; ci < 4; ++ci) {
        f4 v = accF[mi][ci] + bfx_v[ci];
        *(us4*)(bufA + (16 * ci + l15) * BUFA_STR + 16 * mi + 4 * q) = pack4(v);
      }

    // ---- pooling: st[g][c] += sum_n sw[n][g] * fx[n][c], K split in n-halves ----
#pragma unroll
    for (int kh = 0; kh < 2; ++kh) {
      // scalar-write sw^T[g][nloc] half (transpose via LDS)
#pragma unroll
      for (int gi = 0; gi < 4; ++gi)
#pragma unroll
        for (int nn = 0; nn < 2; ++nn) {
          const int ni = 2 * kh + nn;
#pragma unroll
          for (int r = 0; r < 4; ++r) {
            unsigned wv = swp[gi][ni][r >> 1];
            buf2[(16 * gi + 4 * q + r) * BUF2_STR + 16 * nn + l15] =
                (unsigned short)(wv >> (16 * (r & 1)));
          }
        }
      short8 aw[4], bw[4];
#pragma unroll
      for (int mt = 0; mt < 4; ++mt)
        aw[mt] = *(const short8*)(buf2 + (16 * mt + l15) * BUF2_STR + 8 * q);
#pragma unroll
      for (int ct = 0; ct < 4; ++ct)
        bw[ct] = *(const short8*)(bufA + (16 * ct + l15) * BUFA_STR + 32 * kh + 8 * q);
#pragma unroll
      for (int mt = 0; mt < 4; ++mt)
#pragma unroll
        for (int ct = 0; ct < 4; ++ct)
          stacc[mt][ct] = MFMA(aw[mt], bw[ct], stacc[mt][ct]);
    }
  }

  // ---- flush accumulators: non-temporal stores to this block's private slice ----
  float* stp = part_st + (((size_t)blockIdx.x * 8 + h) << 12);
#pragma unroll
  for (int gi = 0; gi < 4; ++gi)
#pragma unroll
    for (int ci = 0; ci < 4; ++ci)
#pragma unroll
      for (int r = 0; r < 4; ++r)
        __builtin_nontemporal_store(stacc[gi][ci][r],
                                    stp + (16 * gi + 4 * q + r) * 64 + 16 * ci + l15);
  float* snp = part_sn + (((size_t)blockIdx.x * 8 + h) << 6);
#pragma unroll
  for (int gi = 0; gi < 4; ++gi)
#pragma unroll
    for (int r = 0; r < 4; ++r) {
      float vv = snacc[gi][r];
      vv += __shfl_xor(vv, 1);
      vv += __shfl_xor(vv, 2);
      vv += __shfl_xor(vv, 4);
      vv += __shfl_xor(vv, 8);
      if (l15 == 0) __builtin_nontemporal_store(vv, snp + 16 * gi + 4 * q + r);
    }
}

// ---------------- reduce: sum 64 block-partials per (b,h) ----------------
__global__ void reduce_kernel(const float* __restrict__ part_st,
                              const float* __restrict__ part_sn,
                              float* __restrict__ stnum,
                              float* __restrict__ snorm) {
  const int gid = blockIdx.x * blockDim.x + threadIdx.x;  // [0, 131072)
  const int i = gid & 4095;
  const int h = (gid >> 12) & 7;
  const int b = gid >> 15;
  const float* p = part_st + ((((size_t)b * 64) * 8 + h) << 12) + i;
  float s = 0.f;
#pragma unroll 8
  for (int blb = 0; blb < 64; ++blb)
    s += __builtin_nontemporal_load(p + (size_t)blb * (8 * 4096));
  stnum[(((size_t)b * 8 + h) << 12) + i] = s;
  if (gid < 2048) {
    const int g = gid & 63, h2 = (gid >> 6) & 7, b2 = gid >> 9;
    const float* ps = part_sn + ((((size_t)b2 * 64) * 8 + h2) << 6) + g;
    float s2 = 0.f;
#pragma unroll 8
    for (int blb = 0; blb < 64; ++blb)
      s2 += __builtin_nontemporal_load(ps + (size_t)blb * (8 * 64));
    snorm[(((size_t)b2 * 8 + h2) << 6) + g] = s2;
  }
}

// ---------------- pass2: tiny slice-token attention (fp32) ----------------
__global__ void pass2_kernel(const float* __restrict__ stnum, const float* __restrict__ snorm,
                             const float* __restrict__ Wq, const float* __restrict__ Wk,
                             const float* __restrict__ Wv, const float* __restrict__ attn_scale,
                             const float* __restrict__ res_scale,
                             unsigned short* __restrict__ ostT) {
  extern __shared__ char lds2[];
  float* st = (float*)lds2;        // [64][65]
  float* kv = st + 64 * 65;        // reused as attn later
  float* kk = kv + 64 * 65;
  float* vv = kk + 64 * 65;
  float* qq = vv + 64 * 65;
  float* nk = qq + 64 * 65;        // [64]
  float* nq = nk + 64;             // [64]
  const int b = blockIdx.x >> 3, h = blockIdx.x & 7;
  const int tid = threadIdx.x;

  float kvr[16], str[16];
#pragma unroll
  for (int j = 0; j < 16; ++j) kvr[j] = 0.f;
  for (int h2 = 0; h2 < 8; ++h2) {
    const float* np = stnum + ((size_t)b * 8 + h2) * 4096;
    const float* sp = snorm + ((size_t)b * 8 + h2) * 64;
#pragma unroll
    for (int j = 0; j < 16; ++j) {
      int idx = tid + 256 * j;
      int g = idx >> 6;
      float v = np[idx] / (sp[g] + 1e-5f);
      kvr[j] += v;
      if (h2 == h) str[j] = v;
    }
  }
#pragma unroll
  for (int j = 0; j < 16; ++j) {
    int idx = tid + 256 * j;
    int g = idx >> 6, d = idx & 63;
    st[g * 65 + d] = str[j];
    kv[g * 65 + d] = kvr[j] * 0.125f;
  }
  __syncthreads();
#pragma unroll 2
  for (int j = 0; j < 16; ++j) {
    int idx = tid + 256 * j;
    int g = idx >> 6, dp = idx & 63;
    float a1 = 0, a2 = 0, a3 = 0;
    for (int dd = 0; dd < 64; ++dd) {
      float kvv = kv[g * 65 + dd], stv = st[g * 65 + dd];
      a1 += kvv * Wk[dp * 64 + dd];
      a2 += kvv * Wv[dp * 64 + dd];
      a3 += stv * Wq[dp * 64 + dd];
    }
    kk[g * 65 + dp] = a1;
    vv[g * 65 + dp] = a2;
    qq[g * 65 + dp] = a3;
  }
  __syncthreads();
  if (tid < 128) {
    int g = tid & 63;
    const float* p = (tid >= 64) ? qq : kk;
    float s = 0;
    for (int d = 0; d < 64; ++d) { float v = p[g * 65 + d]; s += v * v; }
    float nrm = fmaxf(sqrtf(s), 1e-12f);
    ((tid >= 64) ? nq : nk)[g] = nrm;
  }
  __syncthreads();
  const float scale = attn_scale[h];
  float* at = kv;  // reuse
#pragma unroll 2
  for (int j = 0; j < 16; ++j) {
    int idx = tid + 256 * j;
    int g = idx >> 6, s2 = idx & 63;
    float a = 0;
    for (int d = 0; d < 64; ++d) a += qq[g * 65 + d] * kk[s2 * 65 + d];
    at[g * 65 + s2] = a * scale / (nq[g] * nk[s2]);
  }
  __syncthreads();
  if (tid < 64) {
    int g = tid;
    float m = -3.0e38f;
    for (int s2 = 0; s2 < 64; ++s2) m = fmaxf(m, at[g * 65 + s2]);
    float ssum = 0;
    for (int s2 = 0; s2 < 64; ++s2) {
      float e = __expf(at[g * 65 + s2] - m);
      at[g * 65 + s2] = e;
      ssum += e;
    }
    float r = 1.f / ssum;
    for (int s2 = 0; s2 < 64; ++s2) at[g * 65 + s2] *= r;
  }
  __syncthreads();
  const float rs = res_scale[0];
#pragma unroll 2
  for (int j = 0; j < 16; ++j) {
    int idx = tid + 256 * j;
    int g = idx >> 6, d = idx & 63;
    float o = 0;
    for (int s2 = 0; s2 < 64; ++s2) o += at[g * 65 + s2] * vv[s2 * 65 + d];
    o += rs * st[g * 65 + d];
    ostT[(((size_t)b * 8 + h) * 64 + d) * 64 + g] = f2bf(o);  // transposed [d][g]
  }
}

// ---------------- pass3: recompute sw (direct Weff), scatter, final GEMM ----------------
// __launch_bounds__(512, 1): LDS (141 KB) limits to 1 block/CU anyway; don't cap VGPRs.
__launch_bounds__(512, 1)
__global__ void pass3_kernel(const float* __restrict__ x,
                             const unsigned short* __restrict__ weff,
                             const unsigned short* __restrict__ wout,
                             const unsigned short* __restrict__ ostT,
                             const float* __restrict__ beff,
                             const float* __restrict__ temp,
                             const float* __restrict__ bout,
                             float* __restrict__ out) {
  extern __shared__ char lds[];
  const int tid = threadIdx.x;
  const int lane = tid & 63;
  const int h = tid >> 6;
  const int l15 = lane & 15;
  const int q = lane >> 4;
  const int b = blockIdx.x >> 9;          // 512 blocks per batch
  const int n0 = (blockIdx.x & 511) * 64;

  unsigned short* xlds = (unsigned short*)lds;
  unsigned short* buf = (unsigned short*)(lds + XLDS_BYTES + h * BUF2_BYTES);
  unsigned short* ox = (unsigned short*)(lds + XLDS_BYTES + 8 * BUF2_BYTES);

  const float inv_t = 1.0f / temp[h];
  f4 botg[4];
#pragma unroll
  for (int gi = 0; gi < 4; ++gi)
#pragma unroll
    for (int r = 0; r < 4; ++r) botg[gi][r] = beff[h * 64 + 16 * gi + 4 * q + r] * inv_t;
  float bout_v[2];
#pragma unroll
  for (int nt = 0; nt < 2; ++nt) bout_v[nt] = bout[32 * h + 16 * nt + l15];

  const float* xp = x + ((size_t)b * K_N + n0) * K_DIM;
  stage_x(xp, xlds, tid);
  __syncthreads();

  const f4 fz = {0.f, 0.f, 0.f, 0.f};
  // ---- logits GEMM (direct): D[g][n] = sum_k Weff[g][k] * x[n][k] ----
  f4 accL[4][4];
#pragma unroll
  for (int i = 0; i < 4; ++i)
#pragma unroll
    for (int j = 0; j < 4; ++j) accL[i][j] = fz;
#pragma unroll
  for (int ks = 0; ks < 8; ++ks) {
    short8 xb[4], wl[4];
#pragma unroll
    for (int ni = 0; ni < 4; ++ni)
      xb[ni] = *(const short8*)(xlds + (16 * ni + l15) * XS + 32 * ks + 8 * q);
#pragma unroll
    for (int gi = 0; gi < 4; ++gi)
      wl[gi] = *(const short8*)(weff + (size_t)(h * 64 + 16 * gi + l15) * K_DIM + 32 * ks + 8 * q);
#pragma unroll
    for (int gi = 0; gi < 4; ++gi)
#pragma unroll
      for (int ni = 0; ni < 4; ++ni)
        accL[gi][ni] = MFMA(wl[gi], xb[ni], accL[gi][ni]);
  }
#pragma unroll
  for (int gi = 0; gi < 4; ++gi)
#pragma unroll
    for (int ni = 0; ni < 4; ++ni)
      accL[gi][ni] = accL[gi][ni] * inv_t + botg[gi];
  // ---- softmax over g ----
#pragma unroll
  for (int ni = 0; ni < 4; ++ni) {
    float m = -3.0e38f;
#pragma unroll
    for (int gi = 0; gi < 4; ++gi)
#pragma unroll
      for (int r = 0; r < 4; ++r) m = fmaxf(m, accL[gi][ni][r]);
    m = fmaxf(m, __shfl_xor(m, 16));
    m = fmaxf(m, __shfl_xor(m, 32));
    float s = 0.f;
#pragma unroll
    for (int gi = 0; gi < 4; ++gi) {
      f4 e;
#pragma unroll
      for (int r = 0; r < 4; ++r) e[r] = __expf(accL[gi][ni][r] - m);
      accL[gi][ni] = e;
      s += e[0] + e[1] + e[2] + e[3];
    }
    s += __shfl_xor(s, 16);
    s += __shfl_xor(s, 32);
    const float rinv = 1.0f / s;
#pragma unroll
    for (int gi = 0; gi < 4; ++gi) accL[gi][ni] *= rinv;
  }
  // ---- scatter: D[d][n] = sum_g ost^T[d][g] * sw[n][g] ----
  f4 accO[4][4];
#pragma unroll
  for (int i = 0; i < 4; ++i)
#pragma unroll
    for (int j = 0; j < 4; ++j) accO[i][j] = fz;
  const unsigned short* op = ostT + ((size_t)b * 8 + h) * 4096;
#pragma unroll
  for (int kh = 0; kh < 2; ++kh) {
    // fast quad writes: sw[n][gloc] (C rows g contiguous)
#pragma unroll
    for (int gg = 0; gg < 2; ++gg) {
      const int gi = 2 * kh + gg;
#pragma unroll
      for (int ni = 0; ni < 4; ++ni)
        *(us4*)(buf + (16 * ni + l15) * BUF2_STR + 16 * gg + 4 * q) = pack4(accL[gi][ni]);
    }
    short8 ao[4], bo[4];
#pragma unroll
    for (int mt = 0; mt < 4; ++mt)
      ao[mt] = *(const short8*)(op + (16 * mt + l15) * 64 + 32 * kh + 8 * q);
#pragma unroll
    for (int ni = 0; ni < 4; ++ni)
      bo[ni] = *(const short8*)(buf + (16 * ni + l15) * BUF2_STR + 8 * q);
#pragma unroll
    for (int mt = 0; mt < 4; ++mt)
#pragma unroll
      for (int ni = 0; ni < 4; ++ni)
        accO[mt][ni] = MFMA(ao[mt], bo[ni], accO[mt][ni]);
  }
  // write out_x stripe into shared ox[n][c] (fast: C rows d contiguous)
#pragma unroll
  for (int mi = 0; mi < 4; ++mi)
#pragma unroll
    for (int ni = 0; ni < 4; ++ni)
      *(us4*)(ox + (16 * ni + l15) * OX_STR + h * 64 + 16 * mi + 4 * q) = pack4(accO[mi][ni]);
  __syncthreads();

  // ---- final GEMM: out[n][cout] = sum_c ox[n][c]*Wout[cout][c] + bout ----
  f4 accC[4][2];
#pragma unroll
  for (int i = 0; i < 4; ++i)
#pragma unroll
    for (int j = 0; j < 2; ++j) accC[i][j] = fz;
#pragma unroll
  for (int ks = 0; ks < 16; ++ks) {
    short8 ax[4], bw8[2];
#pragma unroll
    for (int mt = 0; mt < 4; ++mt)
      ax[mt] = *(const short8*)(ox + (16 * mt + l15) * OX_STR + 32 * ks + 8 * q);
#pragma unroll
    for (int nt = 0; nt < 2; ++nt)
      bw8[nt] = *(const short8*)(wout + (size_t)(32 * h + 16 * nt + l15) * 512 + 32 * ks + 8 * q);
#pragma unroll
    for (int mt = 0; mt < 4; ++mt)
#pragma unroll
      for (int nt = 0; nt < 2; ++nt)
        accC[mt][nt] = MFMA(ax[mt], bw8[nt], accC[mt][nt]);
  }
  float* op2 = out + ((size_t)b * K_N + n0) * K_DIM;
#pragma unroll
  for (int mt = 0; mt < 4; ++mt)
#pragma unroll
    for (int nt = 0; nt < 2; ++nt) {
      f4 v = accC[mt][nt] + bout_v[nt];
#pragma unroll
      for (int r = 0; r < 4; ++r)
        __builtin_nontemporal_store(
            v[r], op2 + (size_t)(16 * mt + 4 * q + r) * K_DIM + 32 * h + 16 * nt + l15);
    }
}

// ---------------- host launch ----------------
extern "C" void kernel_launch(void* const* d_in, const int* in_sizes, int n_in,
                              void* d_out, int out_size, void* d_ws, size_t ws_size,
                              hipStream_t stream) {
  const float* x    = (const float*)d_in[0];
  const float* Wfx  = (const float*)d_in[1];
  const float* bfx  = (const float*)d_in[2];
  const float* Wx   = (const float*)d_in[3];
  const float* bx   = (const float*)d_in[4];
  const float* Wsl  = (const float*)d_in[5];
  const float* bsl  = (const float*)d_in[6];
  const float* temp = (const float*)d_in[7];
  const float* Wq   = (const float*)d_in[8];
  const float* Wk   = (const float*)d_in[9];
  const float* Wv   = (const float*)d_in[10];
  const float* rs   = (const float*)d_in[11];
  const float* asc  = (const float*)d_in[12];
  const float* Wout = (const float*)d_in[13];
  const float* bout = (const float*)d_in[14];
  float* out = (float*)d_out;
  char* ws = (char*)d_ws;

  unsigned short* wfxb  = (unsigned short*)(ws + WFX_OFF);
  unsigned short* weffb = (unsigned short*)(ws + WX_OFF);
  unsigned short* woutb = (unsigned short*)(ws + WOUT_OFF);
  const float* beffp    = (const float*)(ws + WSL_OFF);
  float* stn = (float*)(ws + STN_OFF);
  float* snr = (float*)(ws + SNORM_OFF);
  unsigned short* ostb = (unsigned short*)(ws + OST_OFF);
  // partial accumulators live in d_out (128 MiB); pass3 overwrites all of d_out later.
  float* pst = out;                    // 8388608 floats = 32 MiB
  float* psn = out + PART_ST_FLOATS;   // 131072 floats  = 512 KiB

  // allow >64KB dynamic LDS (ignore errors; harmless under graph capture)
  (void)hipFuncSetAttribute((const void*)pass1_kernel,
                            hipFuncAttributeMaxDynamicSharedMemorySize, P1_LDS);
  (void)hipFuncSetAttribute((const void*)pass2_kernel,
                            hipFuncAttributeMaxDynamicSharedMemorySize, P2_LDS);
  (void)hipFuncSetAttribute((const void*)pass3_kernel,
                            hipFuncAttributeMaxDynamicSharedMemorySize, P3_LDS);

  prep_kernel<<<256, 256, 0, stream>>>(Wfx, Wx, Wsl, Wout, bx, bsl, ws);
  pass1_kernel<<<256, 512, P1_LDS, stream>>>(x, wfxb, weffb, beffp, bfx, temp, pst, psn);
  reduce_kernel<<<512, 256, 0, stream>>>(pst, psn, stn, snr);
  pass2_kernel<<<32, 256, P2_LDS, stream>>>(stn, snr, Wq, Wk, Wv, asc, rs, ostb);
  pass3_kernel<<<2048, 512, P3_LDS, stream>>>(x, weffb, woutb, ostb, beffp, temp, bout, out);
}

// Round 8
// 1103.859 us; speedup vs baseline: 1.0913x; 1.0913x over previous
//
#include <hip/hip_runtime.h>
#include <stdint.h>

// ---------------- problem constants ----------------
#define K_H    8
#define K_D    64
#define K_G    64
#define K_DIM  256
#define K_INNER 512
#define K_B    4
#define K_N    32768

// ---------------- LDS layout ----------------
#define XS          264                   // x tile row stride (bf16 elems), 528B, 16B aligned
#define XLDS_BYTES  (64 * XS * 2)         // 33792
#define BUFA_STR    72                    // 144B rows, 16B aligned
#define BUFA_BYTES  (64 * BUFA_STR * 2)   // 9216
#define BUF2_STR    40                    // 80B rows, 16B aligned
#define BUF2_BYTES  (64 * BUF2_STR * 2)   // 5120
#define P1_WAVE_BYTES (BUFA_BYTES + BUF2_BYTES)         // 14336
#define P1_LDS      (XLDS_BYTES + 8 * P1_WAVE_BYTES)    // 148480  (<=160K) -> 1 block/CU
#define OX_STR      520                   // 1040B rows, 16B aligned
#define OX_BYTES    (64 * OX_STR * 2)     // 66560
#define P3_LDS      (XLDS_BYTES + 8 * BUF2_BYTES + OX_BYTES)  // 141312 -> 1 block/CU
#define P2_LDS      (5 * 64 * 65 * 4 + 2 * 64 * 4)      // 83712

// ---------------- workspace layout (bytes) — identical to verified baseline ----------------
#define WFX_OFF   0
#define WX_OFF    (512 * 256 * 2)         // holds Weff = Wsl·Wx (bf16, same shape as Wx)
#define WOUT_OFF  (WX_OFF + 512 * 256 * 2)
#define WSL_OFF   (WOUT_OFF + 256 * 512 * 2)  // holds beff = Wsl·bx + bsl (fp32, 512 floats)
#define STN_OFF   (WSL_OFF + 64 * 64 * 2)
#define SNORM_OFF (STN_OFF + 4 * 8 * 64 * 64 * 4)
#define OST_OFF   (SNORM_OFF + 4 * 8 * 64 * 4)
// total = OST_OFF + 4*8*64*64*2 = ~1.6 MB (same as baseline)

// partial accumulators live in d_out (128 MiB; pass3 fully overwrites it later):
#define PART_ST_FLOATS (256 * 8 * 4096)   // 8388608

typedef __attribute__((ext_vector_type(8))) short short8;  // 8 x bf16 (4 VGPRs)
typedef __attribute__((ext_vector_type(4))) float f4;      // MFMA C/D frag; also nt-load vehicle
typedef __attribute__((ext_vector_type(4))) unsigned short us4;

static __device__ __forceinline__ f4 MFMA(short8 a, short8 b, f4 c) {
  return __builtin_amdgcn_mfma_f32_16x16x32_bf16(a, b, c, 0, 0, 0);
}
static __device__ __forceinline__ unsigned short f2bf(float f) {
  union { float f; unsigned u; } v; v.f = f;
  unsigned r = v.u + 0x7FFFu + ((v.u >> 16) & 1u);  // RNE
  return (unsigned short)(r >> 16);
}
static __device__ __forceinline__ us4 pack4(f4 v) {
  us4 p; p[0] = f2bf(v[0]); p[1] = f2bf(v[1]); p[2] = f2bf(v[2]); p[3] = f2bf(v[3]);
  return p;
}
// stage one 64x256 fp32 tile -> bf16 LDS [64][XS], nt loads (use-once stream).
// NOTE (round 6/7 lesson): do NOT hold a full-tile register prefetch across the
// compute phase — 512-thread kernels are pinned at 128 VGPRs (launch_bounds can't
// raise it) and the extra 32 live regs caused ~1 GB of scratch spill traffic.
static __device__ __forceinline__ void stage_x(const float* __restrict__ xp,
                                               unsigned short* xlds, int tid) {
#pragma unroll
  for (int j = 0; j < 8; ++j) {
    int fi = j * 2048 + tid * 4;
    f4 v = __builtin_nontemporal_load((const f4*)(xp + fi));
    int row = fi >> 8, col = fi & 255;
    us4 p; p[0] = f2bf(v[0]); p[1] = f2bf(v[1]); p[2] = f2bf(v[2]); p[3] = f2bf(v[3]);
    *(us4*)(xlds + row * XS + col) = p;
  }
}

// ---------------- prep: weights->bf16, Weff = Wsl·Wx, beff = Wsl·bx + bsl ----------------
__global__ void prep_kernel(const float* __restrict__ Wfx, const float* __restrict__ Wx,
                            const float* __restrict__ Wsl, const float* __restrict__ Wout,
                            const float* __restrict__ bx, const float* __restrict__ bsl,
                            char* __restrict__ ws) {
  int idx = blockIdx.x * blockDim.x + threadIdx.x;
  int stride = gridDim.x * blockDim.x;
  unsigned short* wfxb  = (unsigned short*)(ws + WFX_OFF);
  unsigned short* weffb = (unsigned short*)(ws + WX_OFF);
  unsigned short* woutb = (unsigned short*)(ws + WOUT_OFF);
  float* beff = (float*)(ws + WSL_OFF);
  for (int i = idx; i < 512 * 256; i += stride) wfxb[i] = f2bf(Wfx[i]);
  for (int i = idx; i < 256 * 512; i += stride) woutb[i] = f2bf(Wout[i]);
  // Weff[h][g][k] = sum_d Wsl[g][d] * Wx[h*64+d][k]   (fp32 accumulate, one bf16 round)
  for (int i = idx; i < 8 * 64 * 256; i += stride) {
    int k = i & 255, g = (i >> 8) & 63, hh = i >> 14;
    float s = 0.f;
#pragma unroll 8
    for (int d = 0; d < 64; ++d) s += Wsl[g * 64 + d] * Wx[(size_t)(hh * 64 + d) * 256 + k];
    weffb[i] = f2bf(s);
  }
  // beff[h][g] = sum_d Wsl[g][d] * bx[h*64+d] + bsl[g]
  for (int i = idx; i < 8 * 64; i += stride) {
    int g = i & 63, hh = i >> 6;
    float s = bsl[g];
    for (int d = 0; d < 64; ++d) s += Wsl[g * 64 + d] * bx[hh * 64 + d];
    beff[i] = s;
  }
}

// ---------------- pass1: proj + softmax + pool (persistent, wave = head) ----------------
// Weff collapse: logits = Weff·x directly from the x LDS tile (xm never materialized).
__launch_bounds__(512, 1)
__global__ void pass1_kernel(const float* __restrict__ x,
                             const unsigned short* __restrict__ wfx,
                             const unsigned short* __restrict__ weff,
                             const float* __restrict__ beff,
                             const float* __restrict__ bfx,
                             const float* __restrict__ temp,
                             float* __restrict__ part_st,
                             float* __restrict__ part_sn) {
  extern __shared__ char lds[];
  const int tid = threadIdx.x;
  const int lane = tid & 63;
  const int h = tid >> 6;          // wave id == head
  const int l15 = lane & 15;
  const int q = lane >> 4;
  const int b = blockIdx.x >> 6;   // 64 blocks per batch
  const int blb = blockIdx.x & 63;

  unsigned short* xlds = (unsigned short*)lds;
  unsigned short* bufA = (unsigned short*)(lds + XLDS_BYTES + h * P1_WAVE_BYTES);
  unsigned short* buf2 = bufA + BUFA_BYTES / 2;

  const float inv_t = 1.0f / temp[h];
  float bfx_v[4];
#pragma unroll
  for (int ci = 0; ci < 4; ++ci) bfx_v[ci] = bfx[h * 64 + 16 * ci + l15];
  f4 botg[4];
#pragma unroll
  for (int gi = 0; gi < 4; ++gi)
#pragma unroll
    for (int r = 0; r < 4; ++r) botg[gi][r] = beff[h * 64 + 16 * gi + 4 * q + r] * inv_t;

  const f4 fz = {0.f, 0.f, 0.f, 0.f};
  f4 stacc[4][4];   // st[g][c] accumulator, persistent over the 8 tiles
  f4 snacc[4];      // snorm partial per lane
#pragma unroll
  for (int i = 0; i < 4; ++i) {
    snacc[i] = fz;
#pragma unroll
    for (int j = 0; j < 4; ++j) stacc[i][j] = fz;
  }

  for (int t = 0; t < 8; ++t) {
    const int n0 = (blb * 8 + t) * 64;
    const float* xp = x + ((size_t)b * K_N + n0) * K_DIM;
    __syncthreads();
    stage_x(xp, xlds, tid);
    __syncthreads();

    // ---- logits GEMM (direct): D[g][n] = sum_k Weff[g][k] * x[n][k] ----
    f4 accL[4][4];
#pragma unroll
    for (int i = 0; i < 4; ++i)
#pragma unroll
      for (int j = 0; j < 4; ++j) accL[i][j] = fz;
#pragma unroll
    for (int ks = 0; ks < 8; ++ks) {
      short8 xb[4], wl[4];
#pragma unroll
      for (int ni = 0; ni < 4; ++ni)
        xb[ni] = *(const short8*)(xlds + (16 * ni + l15) * XS + 32 * ks + 8 * q);
#pragma unroll
      for (int gi = 0; gi < 4; ++gi)
        wl[gi] = *(const short8*)(weff + (size_t)(h * 64 + 16 * gi + l15) * K_DIM + 32 * ks + 8 * q);
#pragma unroll
      for (int gi = 0; gi < 4; ++gi)
#pragma unroll
        for (int ni = 0; ni < 4; ++ni)
          accL[gi][ni] = MFMA(wl[gi], xb[ni], accL[gi][ni]);
    }
#pragma unroll
    for (int gi = 0; gi < 4; ++gi)
#pragma unroll
      for (int ni = 0; ni < 4; ++ni)
        accL[gi][ni] = accL[gi][ni] * inv_t + botg[gi];

    // ---- softmax over g (rows): in-lane over 16 regs + shuffle over quads ----
    unsigned swp[4][4][2];
#pragma unroll
    for (int ni = 0; ni < 4; ++ni) {
      float m = -3.0e38f;
#pragma unroll
      for (int gi = 0; gi < 4; ++gi)
#pragma unroll
        for (int r = 0; r < 4; ++r) m = fmaxf(m, accL[gi][ni][r]);
      m = fmaxf(m, __shfl_xor(m, 16));
      m = fmaxf(m, __shfl_xor(m, 32));
      float s = 0.f;
#pragma unroll
      for (int gi = 0; gi < 4; ++gi) {
        f4 e;
#pragma unroll
        for (int r = 0; r < 4; ++r) e[r] = __expf(accL[gi][ni][r] - m);
        accL[gi][ni] = e;
        s += e[0] + e[1] + e[2] + e[3];
      }
      s += __shfl_xor(s, 16);
      s += __shfl_xor(s, 32);
      const float rinv = 1.0f / s;
#pragma unroll
      for (int gi = 0; gi < 4; ++gi) {
        accL[gi][ni] *= rinv;
        snacc[gi] += accL[gi][ni];
        swp[gi][ni][0] = (unsigned)f2bf(accL[gi][ni][0]) | ((unsigned)f2bf(accL[gi][ni][1]) << 16);
        swp[gi][ni][1] = (unsigned)f2bf(accL[gi][ni][2]) | ((unsigned)f2bf(accL[gi][ni][3]) << 16);
      }
    }

    // ---- fx GEMM: D[n][c] = sum_k x[n][k] * Wfx[c][k] ----
    f4 accF[4][4];
#pragma unroll
    for (int i = 0; i < 4; ++i)
#pragma unroll
      for (int j = 0; j < 4; ++j) accF[i][j] = fz;
#pragma unroll
    for (int ks = 0; ks < 8; ++ks) {
      short8 xa[4], wb[4];
#pragma unroll
      for (int mi = 0; mi < 4; ++mi)
        xa[mi] = *(const short8*)(xlds + (16 * mi + l15) * XS + 32 * ks + 8 * q);
#pragma unroll
      for (int ci = 0; ci < 4; ++ci)
        wb[ci] = *(const short8*)(wfx + (size_t)(h * 64 + 16 * ci + l15) * K_DIM + 32 * ks + 8 * q);
#pragma unroll
      for (int mi = 0; mi < 4; ++mi)
#pragma unroll
        for (int ci = 0; ci < 4; ++ci)
          accF[mi][ci] = MFMA(xa[mi], wb[ci], accF[mi][ci]);
    }
    // flush fx^T[c][n] into bufA (fast quad writes along n)
#pragma unroll
    for (int mi = 0; mi < 4; ++mi)
#pragma unroll
      for (int ci = 0; ci < 4; ++ci) {
        f4 v = accF[mi][ci] + bfx_v[ci];
        *(us4*)(bufA + (16 * ci + l15) * BUFA_STR + 16 * mi + 4 * q) = pack4(v);
      }

    // ---- pooling: st[g][c] += sum_n sw[n][g] * fx[n][c], K split in n-halves ----
#pragma unroll
    for (int kh = 0; kh < 2; ++kh) {
      // scalar-write sw^T[g][nloc] half (transpose via LDS)
#pragma unroll
      for (int gi = 0; gi < 4; ++gi)
#pragma unroll
        for (int nn = 0; nn < 2; ++nn) {
          const int ni = 2 * kh + nn;
#pragma unroll
          for (int r = 0; r < 4; ++r) {
            unsigned wv = swp[gi][ni][r >> 1];
            buf2[(16 * gi + 4 * q + r) * BUF2_STR + 16 * nn + l15] =
                (unsigned short)(wv >> (16 * (r & 1)));
          }
        }
      short8 aw[4], bw[4];
#pragma unroll
      for (int mt = 0; mt < 4; ++mt)
        aw[mt] = *(const short8*)(buf2 + (16 * mt + l15) * BUF2_STR + 8 * q);
#pragma unroll
      for (int ct = 0; ct < 4; ++ct)
        bw[ct] = *(const short8*)(bufA + (16 * ct + l15) * BUFA_STR + 32 * kh + 8 * q);
#pragma unroll
      for (int mt = 0; mt < 4; ++mt)
#pragma unroll
        for (int ct = 0; ct < 4; ++ct)
          stacc[mt][ct] = MFMA(aw[mt], bw[ct], stacc[mt][ct]);
    }
  }

  // ---- flush accumulators: non-temporal stores to this block's private slice ----
  float* stp = part_st + (((size_t)blockIdx.x * 8 + h) << 12);
#pragma unroll
  for (int gi = 0; gi < 4; ++gi)
#pragma unroll
    for (int ci = 0; ci < 4; ++ci)
#pragma unroll
      for (int r = 0; r < 4; ++r)
        __builtin_nontemporal_store(stacc[gi][ci][r],
                                    stp + (16 * gi + 4 * q + r) * 64 + 16 * ci + l15);
  float* snp = part_sn + (((size_t)blockIdx.x * 8 + h) << 6);
#pragma unroll
  for (int gi = 0; gi < 4; ++gi)
#pragma unroll
    for (int r = 0; r < 4; ++r) {
      float vv = snacc[gi][r];
      vv += __shfl_xor(vv, 1);
      vv += __shfl_xor(vv, 2);
      vv += __shfl_xor(vv, 4);
      vv += __shfl_xor(vv, 8);
      if (l15 == 0) __builtin_nontemporal_store(vv, snp + 16 * gi + 4 * q + r);
    }
}

// ---------------- reduce: sum 64 block-partials per (b,h) ----------------
__global__ void reduce_kernel(const float* __restrict__ part_st,
                              const float* __restrict__ part_sn,
                              float* __restrict__ stnum,
                              float* __restrict__ snorm) {
  const int gid = blockIdx.x * blockDim.x + threadIdx.x;  // [0, 131072)
  const int i = gid & 4095;
  const int h = (gid >> 12) & 7;
  const int b = gid >> 15;
  const float* p = part_st + ((((size_t)b * 64) * 8 + h) << 12) + i;
  float s = 0.f;
#pragma unroll 8
  for (int blb = 0; blb < 64; ++blb)
    s += __builtin_nontemporal_load(p + (size_t)blb * (8 * 4096));
  stnum[(((size_t)b * 8 + h) << 12) + i] = s;
  if (gid < 2048) {
    const int g = gid & 63, h2 = (gid >> 6) & 7, b2 = gid >> 9;
    const float* ps = part_sn + ((((size_t)b2 * 64) * 8 + h2) << 6) + g;
    float s2 = 0.f;
#pragma unroll 8
    for (int blb = 0; blb < 64; ++blb)
      s2 += __builtin_nontemporal_load(ps + (size_t)blb * (8 * 64));
    snorm[(((size_t)b2 * 8 + h2) << 6) + g] = s2;
  }
}

// ---------------- pass2: tiny slice-token attention (fp32) ----------------
__global__ void pass2_kernel(const float* __restrict__ stnum, const float* __restrict__ snorm,
                             const float* __restrict__ Wq, const float* __restrict__ Wk,
                             const float* __restrict__ Wv, const float* __restrict__ attn_scale,
                             const float* __restrict__ res_scale,
                             unsigned short* __restrict__ ostT) {
  extern __shared__ char lds2[];
  float* st = (float*)lds2;        // [64][65]
  float* kv = st + 64 * 65;        // reused as attn later
  float* kk = kv + 64 * 65;
  float* vv = kk + 64 * 65;
  float* qq = vv + 64 * 65;
  float* nk = qq + 64 * 65;        // [64]
  float* nq = nk + 64;             // [64]
  const int b = blockIdx.x >> 3, h = blockIdx.x & 7;
  const int tid = threadIdx.x;

  float kvr[16], str[16];
#pragma unroll
  for (int j = 0; j < 16; ++j) kvr[j] = 0.f;
  for (int h2 = 0; h2 < 8; ++h2) {
    const float* np = stnum + ((size_t)b * 8 + h2) * 4096;
    const float* sp = snorm + ((size_t)b * 8 + h2) * 64;
#pragma unroll
    for (int j = 0; j < 16; ++j) {
      int idx = tid + 256 * j;
      int g = idx >> 6;
      float v = np[idx] / (sp[g] + 1e-5f);
      kvr[j] += v;
      if (h2 == h) str[j] = v;
    }
  }
#pragma unroll
  for (int j = 0; j < 16; ++j) {
    int idx = tid + 256 * j;
    int g = idx >> 6, d = idx & 63;
    st[g * 65 + d] = str[j];
    kv[g * 65 + d] = kvr[j] * 0.125f;
  }
  __syncthreads();
#pragma unroll 2
  for (int j = 0; j < 16; ++j) {
    int idx = tid + 256 * j;
    int g = idx >> 6, dp = idx & 63;
    float a1 = 0, a2 = 0, a3 = 0;
    for (int dd = 0; dd < 64; ++dd) {
      float kvv = kv[g * 65 + dd], stv = st[g * 65 + dd];
      a1 += kvv * Wk[dp * 64 + dd];
      a2 += kvv * Wv[dp * 64 + dd];
      a3 += stv * Wq[dp * 64 + dd];
    }
    kk[g * 65 + dp] = a1;
    vv[g * 65 + dp] = a2;
    qq[g * 65 + dp] = a3;
  }
  __syncthreads();
  if (tid < 128) {
    int g = tid & 63;
    const float* p = (tid >= 64) ? qq : kk;
    float s = 0;
    for (int d = 0; d < 64; ++d) { float v = p[g * 65 + d]; s += v * v; }
    float nrm = fmaxf(sqrtf(s), 1e-12f);
    ((tid >= 64) ? nq : nk)[g] = nrm;
  }
  __syncthreads();
  const float scale = attn_scale[h];
  float* at = kv;  // reuse
#pragma unroll 2
  for (int j = 0; j < 16; ++j) {
    int idx = tid + 256 * j;
    int g = idx >> 6, s2 = idx & 63;
    float a = 0;
    for (int d = 0; d < 64; ++d) a += qq[g * 65 + d] * kk[s2 * 65 + d];
    at[g * 65 + s2] = a * scale / (nq[g] * nk[s2]);
  }
  __syncthreads();
  if (tid < 64) {
    int g = tid;
    float m = -3.0e38f;
    for (int s2 = 0; s2 < 64; ++s2) m = fmaxf(m, at[g * 65 + s2]);
    float ssum = 0;
    for (int s2 = 0; s2 < 64; ++s2) {
      float e = __expf(at[g * 65 + s2] - m);
      at[g * 65 + s2] = e;
      ssum += e;
    }
    float r = 1.f / ssum;
    for (int s2 = 0; s2 < 64; ++s2) at[g * 65 + s2] *= r;
  }
  __syncthreads();
  const float rs = res_scale[0];
#pragma unroll 2
  for (int j = 0; j < 16; ++j) {
    int idx = tid + 256 * j;
    int g = idx >> 6, d = idx & 63;
    float o = 0;
    for (int s2 = 0; s2 < 64; ++s2) o += at[g * 65 + s2] * vv[s2 * 65 + d];
    o += rs * st[g * 65 + d];
    ostT[(((size_t)b * 8 + h) * 64 + d) * 64 + g] = f2bf(o);  // transposed [d][g]
  }
}

// ---------------- pass3: recompute sw (direct Weff), scatter, final GEMM ----------------
__launch_bounds__(512, 1)
__global__ void pass3_kernel(const float* __restrict__ x,
                             const unsigned short* __restrict__ weff,
                             const unsigned short* __restrict__ wout,
                             const unsigned short* __restrict__ ostT,
                             const float* __restrict__ beff,
                             const float* __restrict__ temp,
                             const float* __restrict__ bout,
                             float* __restrict__ out) {
  extern __shared__ char lds[];
  const int tid = threadIdx.x;
  const int lane = tid & 63;
  const int h = tid >> 6;
  const int l15 = lane & 15;
  const int q = lane >> 4;
  const int b = blockIdx.x >> 9;          // 512 blocks per batch
  const int n0 = (blockIdx.x & 511) * 64;

  unsigned short* xlds = (unsigned short*)lds;
  unsigned short* buf = (unsigned short*)(lds + XLDS_BYTES + h * BUF2_BYTES);
  unsigned short* ox = (unsigned short*)(lds + XLDS_BYTES + 8 * BUF2_BYTES);

  const float inv_t = 1.0f / temp[h];
  f4 botg[4];
#pragma unroll
  for (int gi = 0; gi < 4; ++gi)
#pragma unroll
    for (int r = 0; r < 4; ++r) botg[gi][r] = beff[h * 64 + 16 * gi + 4 * q + r] * inv_t;
  float bout_v[2];
#pragma unroll
  for (int nt = 0; nt < 2; ++nt) bout_v[nt] = bout[32 * h + 16 * nt + l15];

  const float* xp = x + ((size_t)b * K_N + n0) * K_DIM;
  stage_x(xp, xlds, tid);
  __syncthreads();

  const f4 fz = {0.f, 0.f, 0.f, 0.f};
  // ---- logits GEMM (direct): D[g][n] = sum_k Weff[g][k] * x[n][k] ----
  f4 accL[4][4];
#pragma unroll
  for (int i = 0; i < 4; ++i)
#pragma unroll
    for (int j = 0; j < 4; ++j) accL[i][j] = fz;
#pragma unroll
  for (int ks = 0; ks < 8; ++ks) {
    short8 xb[4], wl[4];
#pragma unroll
    for (int ni = 0; ni < 4; ++ni)
      xb[ni] = *(const short8*)(xlds + (16 * ni + l15) * XS + 32 * ks + 8 * q);
#pragma unroll
    for (int gi = 0; gi < 4; ++gi)
      wl[gi] = *(const short8*)(weff + (size_t)(h * 64 + 16 * gi + l15) * K_DIM + 32 * ks + 8 * q);
#pragma unroll
    for (int gi = 0; gi < 4; ++gi)
#pragma unroll
      for (int ni = 0; ni < 4; ++ni)
        accL[gi][ni] = MFMA(wl[gi], xb[ni], accL[gi][ni]);
  }
#pragma unroll
  for (int gi = 0; gi < 4; ++gi)
#pragma unroll
    for (int ni = 0; ni < 4; ++ni)
      accL[gi][ni] = accL[gi][ni] * inv_t + botg[gi];
  // ---- softmax over g ----
#pragma unroll
  for (int ni = 0; ni < 4; ++ni) {
    float m = -3.0e38f;
#pragma unroll
    for (int gi = 0; gi < 4; ++gi)
#pragma unroll
      for (int r = 0; r < 4; ++r) m = fmaxf(m, accL[gi][ni][r]);
    m = fmaxf(m, __shfl_xor(m, 16));
    m = fmaxf(m, __shfl_xor(m, 32));
    float s = 0.f;
#pragma unroll
    for (int gi = 0; gi < 4; ++gi) {
      f4 e;
#pragma unroll
      for (int r = 0; r < 4; ++r) e[r] = __expf(accL[gi][ni][r] - m);
      accL[gi][ni] = e;
      s += e[0] + e[1] + e[2] + e[3];
    }
    s += __shfl_xor(s, 16);
    s += __shfl_xor(s, 32);
    const float rinv = 1.0f / s;
#pragma unroll
    for (int gi = 0; gi < 4; ++gi) accL[gi][ni] *= rinv;
  }
  // ---- scatter: D[d][n] = sum_g ost^T[d][g] * sw[n][g] ----
  f4 accO[4][4];
#pragma unroll
  for (int i = 0; i < 4; ++i)
#pragma unroll
    for (int j = 0; j < 4; ++j) accO[i][j] = fz;
  const unsigned short* op = ostT + ((size_t)b * 8 + h) * 4096;
#pragma unroll
  for (int kh = 0; kh < 2; ++kh) {
    // fast quad writes: sw[n][gloc] (C rows g contiguous)
#pragma unroll
    for (int gg = 0; gg < 2; ++gg) {
      const int gi = 2 * kh + gg;
#pragma unroll
      for (int ni = 0; ni < 4; ++ni)
        *(us4*)(buf + (16 * ni + l15) * BUF2_STR + 16 * gg + 4 * q) = pack4(accL[gi][ni]);
    }
    short8 ao[4], bo[4];
#pragma unroll
    for (int mt = 0; mt < 4; ++mt)
      ao[mt] = *(const short8*)(op + (16 * mt + l15) * 64 + 32 * kh + 8 * q);
#pragma unroll
    for (int ni = 0; ni < 4; ++ni)
      bo[ni] = *(const short8*)(buf + (16 * ni + l15) * BUF2_STR + 8 * q);
#pragma unroll
    for (int mt = 0; mt < 4; ++mt)
#pragma unroll
      for (int ni = 0; ni < 4; ++ni)
        accO[mt][ni] = MFMA(ao[mt], bo[ni], accO[mt][ni]);
  }
  // write out_x stripe into shared ox[n][c] (fast: C rows d contiguous)
#pragma unroll
  for (int mi = 0; mi < 4; ++mi)
#pragma unroll
    for (int ni = 0; ni < 4; ++ni)
      *(us4*)(ox + (16 * ni + l15) * OX_STR + h * 64 + 16 * mi + 4 * q) = pack4(accO[mi][ni]);
  __syncthreads();

  // ---- final GEMM: out[n][cout] = sum_c ox[n][c]*Wout[cout][c] + bout ----
  f4 accC[4][2];
#pragma unroll
  for (int i = 0; i < 4; ++i)
#pragma unroll
    for (int j = 0; j < 2; ++j) accC[i][j] = fz;
#pragma unroll
  for (int ks = 0; ks < 16; ++ks) {
    short8 ax[4], bw8[2];
#pragma unroll
    for (int mt = 0; mt < 4; ++mt)
      ax[mt] = *(const short8*)(ox + (16 * mt + l15) * OX_STR + 32 * ks + 8 * q);
#pragma unroll
    for (int nt = 0; nt < 2; ++nt)
      bw8[nt] = *(const short8*)(wout + (size_t)(32 * h + 16 * nt + l15) * 512 + 32 * ks + 8 * q);
#pragma unroll
    for (int mt = 0; mt < 4; ++mt)
#pragma unroll
      for (int nt = 0; nt < 2; ++nt)
        accC[mt][nt] = MFMA(ax[mt], bw8[nt], accC[mt][nt]);
  }
  float* op2 = out + ((size_t)b * K_N + n0) * K_DIM;
#pragma unroll
  for (int mt = 0; mt < 4; ++mt)
#pragma unroll
    for (int nt = 0; nt < 2; ++nt) {
      f4 v = accC[mt][nt] + bout_v[nt];
#pragma unroll
      for (int r = 0; r < 4; ++r)
        __builtin_nontemporal_store(
            v[r], op2 + (size_t)(16 * mt + 4 * q + r) * K_DIM + 32 * h + 16 * nt + l15);
    }
}

// ---------------- host launch ----------------
extern "C" void kernel_launch(void* const* d_in, const int* in_sizes, int n_in,
                              void* d_out, int out_size, void* d_ws, size_t ws_size,
                              hipStream_t stream) {
  const float* x    = (const float*)d_in[0];
  const float* Wfx  = (const float*)d_in[1];
  const float* bfx  = (const float*)d_in[2];
  const float* Wx   = (const float*)d_in[3];
  const float* bx   = (const float*)d_in[4];
  const float* Wsl  = (const float*)d_in[5];
  const float* bsl  = (const float*)d_in[6];
  const float* temp = (const float*)d_in[7];
  const float* Wq   = (const float*)d_in[8];
  const float* Wk   = (const float*)d_in[9];
  const float* Wv   = (const float*)d_in[10];
  const float* rs   = (const float*)d_in[11];
  const float* asc  = (const float*)d_in[12];
  const float* Wout = (const float*)d_in[13];
  const float* bout = (const float*)d_in[14];
  float* out = (float*)d_out;
  char* ws = (char*)d_ws;

  unsigned short* wfxb  = (unsigned short*)(ws + WFX_OFF);
  unsigned short* weffb = (unsigned short*)(ws + WX_OFF);
  unsigned short* woutb = (unsigned short*)(ws + WOUT_OFF);
  const float* beffp    = (const float*)(ws + WSL_OFF);
  float* stn = (float*)(ws + STN_OFF);
  float* snr = (float*)(ws + SNORM_OFF);
  unsigned short* ostb = (unsigned short*)(ws + OST_OFF);
  // partial accumulators live in d_out (128 MiB); pass3 overwrites all of d_out later.
  float* pst = out;                    // 8388608 floats = 32 MiB
  float* psn = out + PART_ST_FLOATS;   // 131072 floats  = 512 KiB

  // allow >64KB dynamic LDS (ignore errors; harmless under graph capture)
  (void)hipFuncSetAttribute((const void*)pass1_kernel,
                            hipFuncAttributeMaxDynamicSharedMemorySize, P1_LDS);
  (void)hipFuncSetAttribute((const void*)pass2_kernel,
                            hipFuncAttributeMaxDynamicSharedMemorySize, P2_LDS);
  (void)hipFuncSetAttribute((const void*)pass3_kernel,
                            hipFuncAttributeMaxDynamicSharedMemorySize, P3_LDS);

  prep_kernel<<<256, 256, 0, stream>>>(Wfx, Wx, Wsl, Wout, bx, bsl, ws);
  pass1_kernel<<<256, 512, P1_LDS, stream>>>(x, wfxb, weffb, beffp, bfx, temp, pst, psn);
  reduce_kernel<<<512, 256, 0, stream>>>(pst, psn, stn, snr);
  pass2_kernel<<<32, 256, P2_LDS, stream>>>(stn, snr, Wq, Wk, Wv, asc, rs, ostb);
  pass3_kernel<<<2048, 512, P3_LDS, stream>>>(x, wfxb /*unused slot kept for ABI symmetry*/ == wfxb ? weffb : weffb, woutb, ostb, beffp, temp, bout, out);
}

// Round 9
// 899.612 us; speedup vs baseline: 1.3390x; 1.2270x over previous
//
#include <hip/hip_runtime.h>
#include <stdint.h>

// ---------------- problem constants ----------------
#define K_H    8
#define K_D    64
#define K_G    64
#define K_DIM  256
#define K_INNER 512
#define K_B    4
#define K_N    32768

// ---------------- LDS layout ----------------
#define XS          264                   // x tile row stride (bf16 elems), 528B, 16B aligned
#define XLDS_BYTES  (64 * XS * 2)         // 33792
// pass1 per-head buffers (full 64-col rows, 8-col pad): sw^T and fx^T
#define PH_STR      72                    // 144B rows
#define PH_BYTES    (64 * PH_STR * 2)     // 9216
#define P1H_BYTES   (2 * PH_BYTES)        // 18432 per head (buf2 + bufA)
#define P1_LDS      (XLDS_BYTES + 4 * P1H_BYTES)   // 107520 -> 1 block/CU
// pass3 (unchanged structure)
#define BUF2_STR    40
#define BUF2_BYTES  (64 * BUF2_STR * 2)   // 5120
#define OX_STR      520
#define OX_BYTES    (64 * OX_STR * 2)     // 66560
#define P3_LDS      (XLDS_BYTES + 8 * BUF2_BYTES + OX_BYTES)  // 141312
#define P2_LDS      (5 * 64 * 65 * 4 + 2 * 64 * 4)            // 83712

// ---------------- workspace layout (bytes) ----------------
#define WFX_OFF   0
#define WX_OFF    (512 * 256 * 2)         // holds Weff = Wsl·Wx (bf16)
#define WOUT_OFF  (WX_OFF + 512 * 256 * 2)
#define WSL_OFF   (WOUT_OFF + 256 * 512 * 2)  // holds beff (fp32, 512 floats)
#define STN_OFF   (WSL_OFF + 64 * 64 * 2)
#define SNORM_OFF (STN_OFF + 4 * 8 * 64 * 64 * 4)
#define OST_OFF   (SNORM_OFF + 4 * 8 * 64 * 4)

// partial accumulators live in d_out (128 MiB; pass3 fully overwrites it later):
// part_st: 512 blocks x 4 local heads x 4096 fp32 = 32 MiB
// part_sn: 512 x 4 x 2 halves x 64 fp32 = 1 MiB
#define PART_ST_FLOATS (512 * 4 * 4096)   // 8388608

typedef __attribute__((ext_vector_type(8))) short short8;  // 8 x bf16
typedef __attribute__((ext_vector_type(4))) float f4;      // MFMA C/D frag; nt-load vehicle
typedef __attribute__((ext_vector_type(4))) unsigned short us4;

static __device__ __forceinline__ f4 MFMA(short8 a, short8 b, f4 c) {
  return __builtin_amdgcn_mfma_f32_16x16x32_bf16(a, b, c, 0, 0, 0);
}
static __device__ __forceinline__ unsigned short f2bf(float f) {
  union { float f; unsigned u; } v; v.f = f;
  unsigned r = v.u + 0x7FFFu + ((v.u >> 16) & 1u);  // RNE
  return (unsigned short)(r >> 16);
}
static __device__ __forceinline__ us4 pack4(f4 v) {
  us4 p; p[0] = f2bf(v[0]); p[1] = f2bf(v[1]); p[2] = f2bf(v[2]); p[3] = f2bf(v[3]);
  return p;
}
// stage one 64x256 fp32 tile -> bf16 LDS [64][XS], nt loads (use-once stream).
static __device__ __forceinline__ void stage_x(const float* __restrict__ xp,
                                               unsigned short* xlds, int tid) {
#pragma unroll
  for (int j = 0; j < 8; ++j) {
    int fi = j * 2048 + tid * 4;
    f4 v = __builtin_nontemporal_load((const f4*)(xp + fi));
    int row = fi >> 8, col = fi & 255;
    us4 p; p[0] = f2bf(v[0]); p[1] = f2bf(v[1]); p[2] = f2bf(v[2]); p[3] = f2bf(v[3]);
    *(us4*)(xlds + row * XS + col) = p;
  }
}

// ---------------- prep: weights->bf16, Weff = Wsl·Wx, beff = Wsl·bx + bsl ----------------
__global__ void prep_kernel(const float* __restrict__ Wfx, const float* __restrict__ Wx,
                            const float* __restrict__ Wsl, const float* __restrict__ Wout,
                            const float* __restrict__ bx, const float* __restrict__ bsl,
                            char* __restrict__ ws) {
  int idx = blockIdx.x * blockDim.x + threadIdx.x;
  int stride = gridDim.x * blockDim.x;
  unsigned short* wfxb  = (unsigned short*)(ws + WFX_OFF);
  unsigned short* weffb = (unsigned short*)(ws + WX_OFF);
  unsigned short* woutb = (unsigned short*)(ws + WOUT_OFF);
  float* beff = (float*)(ws + WSL_OFF);
  for (int i = idx; i < 512 * 256; i += stride) wfxb[i] = f2bf(Wfx[i]);
  for (int i = idx; i < 256 * 512; i += stride) woutb[i] = f2bf(Wout[i]);
  for (int i = idx; i < 8 * 64 * 256; i += stride) {
    int k = i & 255, g = (i >> 8) & 63, hh = i >> 14;
    float s = 0.f;
#pragma unroll 8
    for (int d = 0; d < 64; ++d) s += Wsl[g * 64 + d] * Wx[(size_t)(hh * 64 + d) * 256 + k];
    weffb[i] = f2bf(s);
  }
  for (int i = idx; i < 8 * 64; i += stride) {
    int g = i & 63, hh = i >> 6;
    float s = bsl[g];
    for (int d = 0; d < 64; ++d) s += Wsl[g * 64 + d] * bx[hh * 64 + d];
    beff[i] = s;
  }
}

// ---------------- pass1: proj + softmax + pool ----------------
// ANTI-SPILL RESTRUCTURE (round-8 lesson: 512-thread kernels are pinned at 128
// VGPRs; the old wave=head layout had ~200 live regs -> 250-650 MB scratch
// traffic per dispatch). Now 2 waves per head: wave `half` owns the c-half of
// fx/stacc (stacc 64->32 regs) and the n-half of sw (accL 64->32); sw^T goes
// straight to LDS in softmax (swp regs eliminated). Worst live ~120 <= 128.
// Grid: 512 blocks = b(4) x ngroup(64) x headgroup(2); 4 heads per block.
__launch_bounds__(512, 1)
__global__ void pass1_kernel(const float* __restrict__ x,
                             const unsigned short* __restrict__ wfx,
                             const unsigned short* __restrict__ weff,
                             const float* __restrict__ beff,
                             const float* __restrict__ bfx,
                             const float* __restrict__ temp,
                             float* __restrict__ part_st,
                             float* __restrict__ part_sn) {
  extern __shared__ char lds[];
  const int tid = threadIdx.x;
  const int lane = tid & 63;
  const int w = tid >> 6;
  const int lh = w >> 1;          // head in block (0..3)
  const int half = w & 1;         // c-half for fx/stacc, n-half for sw
  const int l15 = lane & 15;
  const int q = lane >> 4;
  const int bid = blockIdx.x;
  const int b  = bid >> 7;
  const int ng = (bid & 127) >> 1;
  const int hg = bid & 1;
  const int h  = hg * 4 + lh;     // absolute head

  unsigned short* xlds = (unsigned short*)lds;
  unsigned short* buf2 = (unsigned short*)(lds + XLDS_BYTES + lh * P1H_BYTES); // sw^T [64g][PH_STR]
  unsigned short* bufA = buf2 + PH_BYTES / 2;                                  // fx^T [64c][PH_STR]

  const float inv_t = 1.0f / temp[h];
  const f4 fz = {0.f, 0.f, 0.f, 0.f};
  f4 stacc[4][2];   // st[g][c-half] accumulator, persistent over 8 tiles (32 regs)
  f4 snacc[4];      // snorm partial for this wave's n-half (16 regs)
#pragma unroll
  for (int i = 0; i < 4; ++i) {
    snacc[i] = fz;
    stacc[i][0] = fz; stacc[i][1] = fz;
  }

  for (int t = 0; t < 8; ++t) {
    const int n0 = (ng * 8 + t) * 64;
    const float* xp = x + ((size_t)b * K_N + n0) * K_DIM;
    __syncthreads();
    stage_x(xp, xlds, tid);
    __syncthreads();

    // ---- logits GEMM for this wave's n-half: D[g][n] = Weff[g][:]·x[n][:] ----
    f4 accL[4][2];
#pragma unroll
    for (int i = 0; i < 4; ++i) { accL[i][0] = fz; accL[i][1] = fz; }
#pragma unroll
    for (int ks = 0; ks < 8; ++ks) {
      short8 xb[2], wl[4];
#pragma unroll
      for (int nj = 0; nj < 2; ++nj)
        xb[nj] = *(const short8*)(xlds + (32 * half + 16 * nj + l15) * XS + 32 * ks + 8 * q);
#pragma unroll
      for (int gi = 0; gi < 4; ++gi)
        wl[gi] = *(const short8*)(weff + (size_t)(h * 64 + 16 * gi + l15) * K_DIM + 32 * ks + 8 * q);
#pragma unroll
      for (int gi = 0; gi < 4; ++gi)
#pragma unroll
        for (int nj = 0; nj < 2; ++nj)
          accL[gi][nj] = MFMA(wl[gi], xb[nj], accL[gi][nj]);
    }
    // bias + temperature (beff loaded transiently; keeps persistent regs low)
#pragma unroll
    for (int gi = 0; gi < 4; ++gi) {
      f4 bv = *(const f4*)(beff + h * 64 + 16 * gi + 4 * q);
#pragma unroll
      for (int nj = 0; nj < 2; ++nj)
        accL[gi][nj] = (accL[gi][nj] + bv) * inv_t;
    }

    // ---- softmax over g; write sw^T bf16 directly into shared buf2 ----
#pragma unroll
    for (int nj = 0; nj < 2; ++nj) {
      float m = -3.0e38f;
#pragma unroll
      for (int gi = 0; gi < 4; ++gi)
#pragma unroll
        for (int r = 0; r < 4; ++r) m = fmaxf(m, accL[gi][nj][r]);
      m = fmaxf(m, __shfl_xor(m, 16));
      m = fmaxf(m, __shfl_xor(m, 32));
      float s = 0.f;
#pragma unroll
      for (int gi = 0; gi < 4; ++gi) {
        f4 e;
#pragma unroll
        for (int r = 0; r < 4; ++r) e[r] = __expf(accL[gi][nj][r] - m);
        accL[gi][nj] = e;
        s += e[0] + e[1] + e[2] + e[3];
      }
      s += __shfl_xor(s, 16);
      s += __shfl_xor(s, 32);
      const float rinv = 1.0f / s;
#pragma unroll
      for (int gi = 0; gi < 4; ++gi) {
        accL[gi][nj] *= rinv;
        snacc[gi] += accL[gi][nj];
#pragma unroll
        for (int r = 0; r < 4; ++r)
          buf2[(16 * gi + 4 * q + r) * PH_STR + 32 * half + 16 * nj + l15] =
              f2bf(accL[gi][nj][r]);
      }
    }

    // ---- fx GEMM for this wave's c-half: D[n][c] = x[n][:]·Wfx[c][:] ----
    f4 accF[4][2];
#pragma unroll
    for (int i = 0; i < 4; ++i) { accF[i][0] = fz; accF[i][1] = fz; }
#pragma unroll
    for (int ks = 0; ks < 8; ++ks) {
      short8 xa[4], wb[2];
#pragma unroll
      for (int mi = 0; mi < 4; ++mi)
        xa[mi] = *(const short8*)(xlds + (16 * mi + l15) * XS + 32 * ks + 8 * q);
#pragma unroll
      for (int cj = 0; cj < 2; ++cj)
        wb[cj] = *(const short8*)(wfx + (size_t)(h * 64 + 32 * half + 16 * cj + l15) * K_DIM +
                                  32 * ks + 8 * q);
#pragma unroll
      for (int mi = 0; mi < 4; ++mi)
#pragma unroll
        for (int cj = 0; cj < 2; ++cj)
          accF[mi][cj] = MFMA(xa[mi], wb[cj], accF[mi][cj]);
    }
    // flush fx^T[c][n] (own c-rows; bias loaded transiently)
#pragma unroll
    for (int cj = 0; cj < 2; ++cj) {
      const float bfv = bfx[h * 64 + 32 * half + 16 * cj + l15];
#pragma unroll
      for (int mi = 0; mi < 4; ++mi) {
        f4 v = accF[mi][cj] + bfv;
        *(us4*)(bufA + (32 * half + 16 * cj + l15) * PH_STR + 16 * mi + 4 * q) = pack4(v);
      }
    }
    __syncthreads();   // wave pair: sw^T + fx^T complete before pooling

    // ---- pooling: stacc[g][c-half] += sum_n sw^T[g][n] * fx^T[c][n] ----
#pragma unroll
    for (int kh = 0; kh < 2; ++kh) {
      short8 aw[4], bw[2];
#pragma unroll
      for (int mt = 0; mt < 4; ++mt)
        aw[mt] = *(const short8*)(buf2 + (16 * mt + l15) * PH_STR + 32 * kh + 8 * q);
#pragma unroll
      for (int ct = 0; ct < 2; ++ct)
        bw[ct] = *(const short8*)(bufA + (32 * half + 16 * ct + l15) * PH_STR + 32 * kh + 8 * q);
#pragma unroll
      for (int mt = 0; mt < 4; ++mt)
#pragma unroll
        for (int ct = 0; ct < 2; ++ct)
          stacc[mt][ct] = MFMA(aw[mt], bw[ct], stacc[mt][ct]);
    }
  }

  // ---- flush partials (own c-half columns of this head's slice) ----
  float* stp = part_st + (((size_t)bid * 4 + lh) << 12);
#pragma unroll
  for (int mt = 0; mt < 4; ++mt)
#pragma unroll
    for (int ct = 0; ct < 2; ++ct)
#pragma unroll
      for (int r = 0; r < 4; ++r)
        __builtin_nontemporal_store(
            stacc[mt][ct][r],
            stp + (16 * mt + 4 * q + r) * 64 + 32 * half + 16 * ct + l15);
  float* snp = part_sn + ((((size_t)bid * 4 + lh) * 2 + half) << 6);
#pragma unroll
  for (int gi = 0; gi < 4; ++gi)
#pragma unroll
    for (int r = 0; r < 4; ++r) {
      float vv = snacc[gi][r];
      vv += __shfl_xor(vv, 1);
      vv += __shfl_xor(vv, 2);
      vv += __shfl_xor(vv, 4);
      vv += __shfl_xor(vv, 8);
      if (l15 == 0) __builtin_nontemporal_store(vv, snp + 16 * gi + 4 * q + r);
    }
}

// ---------------- reduce: sum partials per (b,h) ----------------
// part_st slice for (b, ng, hg, lh) at ((b*128 + ng*2 + hg)*4 + lh)*4096.
__global__ void reduce_kernel(const float* __restrict__ part_st,
                              const float* __restrict__ part_sn,
                              float* __restrict__ stnum,
                              float* __restrict__ snorm) {
  const int gid = blockIdx.x * blockDim.x + threadIdx.x;  // [0, 131072)
  const int i = gid & 4095;
  const int h = (gid >> 12) & 7;
  const int b = gid >> 15;
  const float* p = part_st + ((size_t)(((b * 128) + (h >> 2)) * 4 + (h & 3)) << 12) + i;
  float s = 0.f;
#pragma unroll 8
  for (int ng = 0; ng < 64; ++ng)
    s += __builtin_nontemporal_load(p + (size_t)ng * (2 * 4 * 4096));
  stnum[(((size_t)b * 8 + h) << 12) + i] = s;
  if (gid < 2048) {
    const int g = gid & 63, h2 = (gid >> 6) & 7, b2 = gid >> 9;
    const float* ps = part_sn +
        ((size_t)((((b2 * 128) + (h2 >> 2)) * 4 + (h2 & 3)) * 2) << 6) + g;
    float s2 = 0.f;
#pragma unroll 8
    for (int ng = 0; ng < 64; ++ng) {
      s2 += __builtin_nontemporal_load(ps + (size_t)ng * 1024);
      s2 += __builtin_nontemporal_load(ps + (size_t)ng * 1024 + 64);
    }
    snorm[(((size_t)b2 * 8 + h2) << 6) + g] = s2;
  }
}

// ---------------- pass2: tiny slice-token attention (fp32) ----------------
__global__ void pass2_kernel(const float* __restrict__ stnum, const float* __restrict__ snorm,
                             const float* __restrict__ Wq, const float* __restrict__ Wk,
                             const float* __restrict__ Wv, const float* __restrict__ attn_scale,
                             const float* __restrict__ res_scale,
                             unsigned short* __restrict__ ostT) {
  extern __shared__ char lds2[];
  float* st = (float*)lds2;        // [64][65]
  float* kv = st + 64 * 65;        // reused as attn later
  float* kk = kv + 64 * 65;
  float* vv = kk + 64 * 65;
  float* qq = vv + 64 * 65;
  float* nk = qq + 64 * 65;        // [64]
  float* nq = nk + 64;             // [64]
  const int b = blockIdx.x >> 3, h = blockIdx.x & 7;
  const int tid = threadIdx.x;

  float kvr[16], str[16];
#pragma unroll
  for (int j = 0; j < 16; ++j) kvr[j] = 0.f;
  for (int h2 = 0; h2 < 8; ++h2) {
    const float* np = stnum + ((size_t)b * 8 + h2) * 4096;
    const float* sp = snorm + ((size_t)b * 8 + h2) * 64;
#pragma unroll
    for (int j = 0; j < 16; ++j) {
      int idx = tid + 256 * j;
      int g = idx >> 6;
      float v = np[idx] / (sp[g] + 1e-5f);
      kvr[j] += v;
      if (h2 == h) str[j] = v;
    }
  }
#pragma unroll
  for (int j = 0; j < 16; ++j) {
    int idx = tid + 256 * j;
    int g = idx >> 6, d = idx & 63;
    st[g * 65 + d] = str[j];
    kv[g * 65 + d] = kvr[j] * 0.125f;
  }
  __syncthreads();
#pragma unroll 2
  for (int j = 0; j < 16; ++j) {
    int idx = tid + 256 * j;
    int g = idx >> 6, dp = idx & 63;
    float a1 = 0, a2 = 0, a3 = 0;
    for (int dd = 0; dd < 64; ++dd) {
      float kvv = kv[g * 65 + dd], stv = st[g * 65 + dd];
      a1 += kvv * Wk[dp * 64 + dd];
      a2 += kvv * Wv[dp * 64 + dd];
      a3 += stv * Wq[dp * 64 + dd];
    }
    kk[g * 65 + dp] = a1;
    vv[g * 65 + dp] = a2;
    qq[g * 65 + dp] = a3;
  }
  __syncthreads();
  if (tid < 128) {
    int g = tid & 63;
    const float* p = (tid >= 64) ? qq : kk;
    float s = 0;
    for (int d = 0; d < 64; ++d) { float v = p[g * 65 + d]; s += v * v; }
    float nrm = fmaxf(sqrtf(s), 1e-12f);
    ((tid >= 64) ? nq : nk)[g] = nrm;
  }
  __syncthreads();
  const float scale = attn_scale[h];
  float* at = kv;  // reuse
#pragma unroll 2
  for (int j = 0; j < 16; ++j) {
    int idx = tid + 256 * j;
    int g = idx >> 6, s2 = idx & 63;
    float a = 0;
    for (int d = 0; d < 64; ++d) a += qq[g * 65 + d] * kk[s2 * 65 + d];
    at[g * 65 + s2] = a * scale / (nq[g] * nk[s2]);
  }
  __syncthreads();
  if (tid < 64) {
    int g = tid;
    float m = -3.0e38f;
    for (int s2 = 0; s2 < 64; ++s2) m = fmaxf(m, at[g * 65 + s2]);
    float ssum = 0;
    for (int s2 = 0; s2 < 64; ++s2) {
      float e = __expf(at[g * 65 + s2] - m);
      at[g * 65 + s2] = e;
      ssum += e;
    }
    float r = 1.f / ssum;
    for (int s2 = 0; s2 < 64; ++s2) at[g * 65 + s2] *= r;
  }
  __syncthreads();
  const float rs = res_scale[0];
#pragma unroll 2
  for (int j = 0; j < 16; ++j) {
    int idx = tid + 256 * j;
    int g = idx >> 6, d = idx & 63;
    float o = 0;
    for (int s2 = 0; s2 < 64; ++s2) o += at[g * 65 + s2] * vv[s2 * 65 + d];
    o += rs * st[g * 65 + d];
    ostT[(((size_t)b * 8 + h) * 64 + d) * 64 + g] = f2bf(o);  // transposed [d][g]
  }
}

// ---------------- pass3: recompute sw (direct Weff), scatter, final GEMM ----------------
__launch_bounds__(512, 1)
__global__ void pass3_kernel(const float* __restrict__ x,
                             const unsigned short* __restrict__ weff,
                             const unsigned short* __restrict__ wout,
                             const unsigned short* __restrict__ ostT,
                             const float* __restrict__ beff,
                             const float* __restrict__ temp,
                             const float* __restrict__ bout,
                             float* __restrict__ out) {
  extern __shared__ char lds[];
  const int tid = threadIdx.x;
  const int lane = tid & 63;
  const int h = tid >> 6;
  const int l15 = lane & 15;
  const int q = lane >> 4;
  const int b = blockIdx.x >> 9;          // 512 blocks per batch
  const int n0 = (blockIdx.x & 511) * 64;

  unsigned short* xlds = (unsigned short*)lds;
  unsigned short* buf = (unsigned short*)(lds + XLDS_BYTES + h * BUF2_BYTES);
  unsigned short* ox = (unsigned short*)(lds + XLDS_BYTES + 8 * BUF2_BYTES);

  const float inv_t = 1.0f / temp[h];
  f4 botg[4];
#pragma unroll
  for (int gi = 0; gi < 4; ++gi)
#pragma unroll
    for (int r = 0; r < 4; ++r) botg[gi][r] = beff[h * 64 + 16 * gi + 4 * q + r] * inv_t;
  float bout_v[2];
#pragma unroll
  for (int nt = 0; nt < 2; ++nt) bout_v[nt] = bout[32 * h + 16 * nt + l15];

  const float* xp = x + ((size_t)b * K_N + n0) * K_DIM;
  stage_x(xp, xlds, tid);
  __syncthreads();

  const f4 fz = {0.f, 0.f, 0.f, 0.f};
  // ---- logits GEMM (direct Weff) ----
  f4 accL[4][4];
#pragma unroll
  for (int i = 0; i < 4; ++i)
#pragma unroll
    for (int j = 0; j < 4; ++j) accL[i][j] = fz;
#pragma unroll
  for (int ks = 0; ks < 8; ++ks) {
    short8 xb[4], wl[4];
#pragma unroll
    for (int ni = 0; ni < 4; ++ni)
      xb[ni] = *(const short8*)(xlds + (16 * ni + l15) * XS + 32 * ks + 8 * q);
#pragma unroll
    for (int gi = 0; gi < 4; ++gi)
      wl[gi] = *(const short8*)(weff + (size_t)(h * 64 + 16 * gi + l15) * K_DIM + 32 * ks + 8 * q);
#pragma unroll
    for (int gi = 0; gi < 4; ++gi)
#pragma unroll
      for (int ni = 0; ni < 4; ++ni)
        accL[gi][ni] = MFMA(wl[gi], xb[ni], accL[gi][ni]);
  }
#pragma unroll
  for (int gi = 0; gi < 4; ++gi)
#pragma unroll
    for (int ni = 0; ni < 4; ++ni)
      accL[gi][ni] = accL[gi][ni] * inv_t + botg[gi];
  // ---- softmax over g ----
#pragma unroll
  for (int ni = 0; ni < 4; ++ni) {
    float m = -3.0e38f;
#pragma unroll
    for (int gi = 0; gi < 4; ++gi)
#pragma unroll
      for (int r = 0; r < 4; ++r) m = fmaxf(m, accL[gi][ni][r]);
    m = fmaxf(m, __shfl_xor(m, 16));
    m = fmaxf(m, __shfl_xor(m, 32));
    float s = 0.f;
#pragma unroll
    for (int gi = 0; gi < 4; ++gi) {
      f4 e;
#pragma unroll
      for (int r = 0; r < 4; ++r) e[r] = __expf(accL[gi][ni][r] - m);
      accL[gi][ni] = e;
      s += e[0] + e[1] + e[2] + e[3];
    }
    s += __shfl_xor(s, 16);
    s += __shfl_xor(s, 32);
    const float rinv = 1.0f / s;
#pragma unroll
    for (int gi = 0; gi < 4; ++gi) accL[gi][ni] *= rinv;
  }
  // ---- scatter: D[d][n] = sum_g ost^T[d][g] * sw[n][g] ----
  f4 accO[4][4];
#pragma unroll
  for (int i = 0; i < 4; ++i)
#pragma unroll
    for (int j = 0; j < 4; ++j) accO[i][j] = fz;
  const unsigned short* op = ostT + ((size_t)b * 8 + h) * 4096;
#pragma unroll
  for (int kh = 0; kh < 2; ++kh) {
#pragma unroll
    for (int gg = 0; gg < 2; ++gg) {
      const int gi = 2 * kh + gg;
#pragma unroll
      for (int ni = 0; ni < 4; ++ni)
        *(us4*)(buf + (16 * ni + l15) * BUF2_STR + 16 * gg + 4 * q) = pack4(accL[gi][ni]);
    }
    short8 ao[4], bo[4];
#pragma unroll
    for (int mt = 0; mt < 4; ++mt)
      ao[mt] = *(const short8*)(op + (16 * mt + l15) * 64 + 32 * kh + 8 * q);
#pragma unroll
    for (int ni = 0; ni < 4; ++ni)
      bo[ni] = *(const short8*)(buf + (16 * ni + l15) * BUF2_STR + 8 * q);
#pragma unroll
    for (int mt = 0; mt < 4; ++mt)
#pragma unroll
      for (int ni = 0; ni < 4; ++ni)
        accO[mt][ni] = MFMA(ao[mt], bo[ni], accO[mt][ni]);
  }
#pragma unroll
  for (int mi = 0; mi < 4; ++mi)
#pragma unroll
    for (int ni = 0; ni < 4; ++ni)
      *(us4*)(ox + (16 * ni + l15) * OX_STR + h * 64 + 16 * mi + 4 * q) = pack4(accO[mi][ni]);
  __syncthreads();

  // ---- final GEMM: out = ox·Wout^T + bout ----
  f4 accC[4][2];
#pragma unroll
  for (int i = 0; i < 4; ++i)
#pragma unroll
    for (int j = 0; j < 2; ++j) accC[i][j] = fz;
#pragma unroll
  for (int ks = 0; ks < 16; ++ks) {
    short8 ax[4], bw8[2];
#pragma unroll
    for (int mt = 0; mt < 4; ++mt)
      ax[mt] = *(const short8*)(ox + (16 * mt + l15) * OX_STR + 32 * ks + 8 * q);
#pragma unroll
    for (int nt = 0; nt < 2; ++nt)
      bw8[nt] = *(const short8*)(wout + (size_t)(32 * h + 16 * nt + l15) * 512 + 32 * ks + 8 * q);
#pragma unroll
    for (int mt = 0; mt < 4; ++mt)
#pragma unroll
      for (int nt = 0; nt < 2; ++nt)
        accC[mt][nt] = MFMA(ax[mt], bw8[nt], accC[mt][nt]);
  }
  float* op2 = out + ((size_t)b * K_N + n0) * K_DIM;
#pragma unroll
  for (int mt = 0; mt < 4; ++mt)
#pragma unroll
    for (int nt = 0; nt < 2; ++nt) {
      f4 v = accC[mt][nt] + bout_v[nt];
#pragma unroll
      for (int r = 0; r < 4; ++r)
        __builtin_nontemporal_store(
            v[r], op2 + (size_t)(16 * mt + 4 * q + r) * K_DIM + 32 * h + 16 * nt + l15);
    }
}

// ---------------- host launch ----------------
extern "C" void kernel_launch(void* const* d_in, const int* in_sizes, int n_in,
                              void* d_out, int out_size, void* d_ws, size_t ws_size,
                              hipStream_t stream) {
  const float* x    = (const float*)d_in[0];
  const float* Wfx  = (const float*)d_in[1];
  const float* bfx  = (const float*)d_in[2];
  const float* Wx   = (const float*)d_in[3];
  const float* bx   = (const float*)d_in[4];
  const float* Wsl  = (const float*)d_in[5];
  const float* bsl  = (const float*)d_in[6];
  const float* temp = (const float*)d_in[7];
  const float* Wq   = (const float*)d_in[8];
  const float* Wk   = (const float*)d_in[9];
  const float* Wv   = (const float*)d_in[10];
  const float* rs   = (const float*)d_in[11];
  const float* asc  = (const float*)d_in[12];
  const float* Wout = (const float*)d_in[13];
  const float* bout = (const float*)d_in[14];
  float* out = (float*)d_out;
  char* ws = (char*)d_ws;

  unsigned short* wfxb  = (unsigned short*)(ws + WFX_OFF);
  unsigned short* weffb = (unsigned short*)(ws + WX_OFF);
  unsigned short* woutb = (unsigned short*)(ws + WOUT_OFF);
  const float* beffp    = (const float*)(ws + WSL_OFF);
  float* stn = (float*)(ws + STN_OFF);
  float* snr = (float*)(ws + SNORM_OFF);
  unsigned short* ostb = (unsigned short*)(ws + OST_OFF);
  // partial accumulators live in d_out (128 MiB); pass3 overwrites all of d_out later.
  float* pst = out;                    // 8388608 floats = 32 MiB
  float* psn = out + PART_ST_FLOATS;   // 262144 floats  = 1 MiB

  (void)hipFuncSetAttribute((const void*)pass1_kernel,
                            hipFuncAttributeMaxDynamicSharedMemorySize, P1_LDS);
  (void)hipFuncSetAttribute((const void*)pass2_kernel,
                            hipFuncAttributeMaxDynamicSharedMemorySize, P2_LDS);
  (void)hipFuncSetAttribute((const void*)pass3_kernel,
                            hipFuncAttributeMaxDynamicSharedMemorySize, P3_LDS);

  prep_kernel<<<256, 256, 0, stream>>>(Wfx, Wx, Wsl, Wout, bx, bsl, ws);
  pass1_kernel<<<512, 512, P1_LDS, stream>>>(x, wfxb, weffb, beffp, bfx, temp, pst, psn);
  reduce_kernel<<<512, 256, 0, stream>>>(pst, psn, stn, snr);
  pass2_kernel<<<32, 256, P2_LDS, stream>>>(stn, snr, Wq, Wk, Wv, asc, rs, ostb);
  pass3_kernel<<<2048, 512, P3_LDS, stream>>>(x, weffb, woutb, ostb, beffp, temp, bout, out);
}

// Round 10
// 896.143 us; speedup vs baseline: 1.3442x; 1.0039x over previous
//
#include <hip/hip_runtime.h>
#include <stdint.h>

// ---------------- problem constants ----------------
#define K_H    8
#define K_D    64
#define K_G    64
#define K_DIM  256
#define K_INNER 512
#define K_B    4
#define K_N    32768

// ---------------- LDS layout ----------------
#define XS          264                   // x tile row stride (bf16 elems), 528B, 16B aligned
#define XLDS_BYTES  (64 * XS * 2)         // 33792
// pass1 per-head buffers (full 64-col rows, 8-col pad): sw^T and fx^T
#define PH_STR      72                    // 144B rows
#define PH_BYTES    (64 * PH_STR * 2)     // 9216
#define P1H_BYTES   (2 * PH_BYTES)        // 18432 per head (buf2 + bufA)
#define P1_LDS      (XLDS_BYTES + 4 * P1H_BYTES)   // 107520 -> 1 block/CU
// pass3: ox ALIASES xlds+buf (dead by the time ox is written) -> 74752 B -> 2 blocks/CU
#define BUF2_STR    40
#define BUF2_BYTES  (64 * BUF2_STR * 2)   // 5120
#define OX_STR      520
#define OX_BYTES    (64 * OX_STR * 2)     // 66560  (< XLDS_BYTES + 8*BUF2_BYTES = 74752)
#define P3_LDS      (XLDS_BYTES + 8 * BUF2_BYTES)  // 74752 -> 2 blocks/CU at 128 VGPR
#define P2_LDS      (5 * 64 * 65 * 4 + 2 * 64 * 4)            // 83712

// ---------------- workspace layout (bytes) ----------------
#define WFX_OFF   0
#define WX_OFF    (512 * 256 * 2)         // holds Weff = Wsl·Wx (bf16)
#define WOUT_OFF  (WX_OFF + 512 * 256 * 2)
#define WSL_OFF   (WOUT_OFF + 256 * 512 * 2)  // holds beff (fp32, 512 floats)
#define STN_OFF   (WSL_OFF + 64 * 64 * 2)
#define SNORM_OFF (STN_OFF + 4 * 8 * 64 * 64 * 4)
#define OST_OFF   (SNORM_OFF + 4 * 8 * 64 * 4)

// partial accumulators live in d_out (128 MiB; pass3 fully overwrites it later):
// part_st: 512 blocks x 4 local heads x 4096 fp32 = 32 MiB
// part_sn: 512 x 4 x 2 halves x 64 fp32 = 1 MiB
#define PART_ST_FLOATS (512 * 4 * 4096)   // 8388608

typedef __attribute__((ext_vector_type(8))) short short8;  // 8 x bf16
typedef __attribute__((ext_vector_type(4))) float f4;      // MFMA C/D frag; nt-load vehicle
typedef __attribute__((ext_vector_type(4))) unsigned short us4;

static __device__ __forceinline__ f4 MFMA(short8 a, short8 b, f4 c) {
  return __builtin_amdgcn_mfma_f32_16x16x32_bf16(a, b, c, 0, 0, 0);
}
static __device__ __forceinline__ unsigned short f2bf(float f) {
  union { float f; unsigned u; } v; v.f = f;
  unsigned r = v.u + 0x7FFFu + ((v.u >> 16) & 1u);  // RNE
  return (unsigned short)(r >> 16);
}
static __device__ __forceinline__ us4 pack4(f4 v) {
  us4 p; p[0] = f2bf(v[0]); p[1] = f2bf(v[1]); p[2] = f2bf(v[2]); p[3] = f2bf(v[3]);
  return p;
}
// stage one 64x256 fp32 tile -> bf16 LDS [64][XS], nt loads (use-once stream).
static __device__ __forceinline__ void stage_x(const float* __restrict__ xp,
                                               unsigned short* xlds, int tid) {
#pragma unroll
  for (int j = 0; j < 8; ++j) {
    int fi = j * 2048 + tid * 4;
    f4 v = __builtin_nontemporal_load((const f4*)(xp + fi));
    int row = fi >> 8, col = fi & 255;
    us4 p; p[0] = f2bf(v[0]); p[1] = f2bf(v[1]); p[2] = f2bf(v[2]); p[3] = f2bf(v[3]);
    *(us4*)(xlds + row * XS + col) = p;
  }
}

// ---------------- prep: weights->bf16, Weff = Wsl·Wx, beff = Wsl·bx + bsl ----------------
__global__ void prep_kernel(const float* __restrict__ Wfx, const float* __restrict__ Wx,
                            const float* __restrict__ Wsl, const float* __restrict__ Wout,
                            const float* __restrict__ bx, const float* __restrict__ bsl,
                            char* __restrict__ ws) {
  int idx = blockIdx.x * blockDim.x + threadIdx.x;
  int stride = gridDim.x * blockDim.x;
  unsigned short* wfxb  = (unsigned short*)(ws + WFX_OFF);
  unsigned short* weffb = (unsigned short*)(ws + WX_OFF);
  unsigned short* woutb = (unsigned short*)(ws + WOUT_OFF);
  float* beff = (float*)(ws + WSL_OFF);
  for (int i = idx; i < 512 * 256; i += stride) wfxb[i] = f2bf(Wfx[i]);
  for (int i = idx; i < 256 * 512; i += stride) woutb[i] = f2bf(Wout[i]);
  for (int i = idx; i < 8 * 64 * 256; i += stride) {
    int k = i & 255, g = (i >> 8) & 63, hh = i >> 14;
    float s = 0.f;
#pragma unroll 8
    for (int d = 0; d < 64; ++d) s += Wsl[g * 64 + d] * Wx[(size_t)(hh * 64 + d) * 256 + k];
    weffb[i] = f2bf(s);
  }
  for (int i = idx; i < 8 * 64; i += stride) {
    int g = i & 63, hh = i >> 6;
    float s = bsl[g];
    for (int d = 0; d < 64; ++d) s += Wsl[g * 64 + d] * bx[hh * 64 + d];
    beff[i] = s;
  }
}

// ---------------- pass1: proj + softmax + pool ----------------
// ANTI-SPILL: 2 waves per head (4 heads/block); stacc/accL halved, sw^T straight
// to LDS. Live regs ~120 <= the 128-VGPR hard cap for 512-thread kernels.
// (Verified round 9: WRITE 655->140 MB, dur 572->336 us.)
__launch_bounds__(512, 1)
__global__ void pass1_kernel(const float* __restrict__ x,
                             const unsigned short* __restrict__ wfx,
                             const unsigned short* __restrict__ weff,
                             const float* __restrict__ beff,
                             const float* __restrict__ bfx,
                             const float* __restrict__ temp,
                             float* __restrict__ part_st,
                             float* __restrict__ part_sn) {
  extern __shared__ char lds[];
  const int tid = threadIdx.x;
  const int lane = tid & 63;
  const int w = tid >> 6;
  const int lh = w >> 1;          // head in block (0..3)
  const int half = w & 1;         // c-half for fx/stacc, n-half for sw
  const int l15 = lane & 15;
  const int q = lane >> 4;
  const int bid = blockIdx.x;
  const int b  = bid >> 7;
  const int ng = (bid & 127) >> 1;
  const int hg = bid & 1;
  const int h  = hg * 4 + lh;     // absolute head

  unsigned short* xlds = (unsigned short*)lds;
  unsigned short* buf2 = (unsigned short*)(lds + XLDS_BYTES + lh * P1H_BYTES); // sw^T [64g][PH_STR]
  unsigned short* bufA = buf2 + PH_BYTES / 2;                                  // fx^T [64c][PH_STR]

  const float inv_t = 1.0f / temp[h];
  const f4 fz = {0.f, 0.f, 0.f, 0.f};
  f4 stacc[4][2];   // st[g][c-half] accumulator, persistent over 8 tiles (32 regs)
  f4 snacc[4];      // snorm partial for this wave's n-half (16 regs)
#pragma unroll
  for (int i = 0; i < 4; ++i) {
    snacc[i] = fz;
    stacc[i][0] = fz; stacc[i][1] = fz;
  }

  for (int t = 0; t < 8; ++t) {
    const int n0 = (ng * 8 + t) * 64;
    const float* xp = x + ((size_t)b * K_N + n0) * K_DIM;
    __syncthreads();
    stage_x(xp, xlds, tid);
    __syncthreads();

    // ---- logits GEMM for this wave's n-half: D[g][n] = Weff[g][:]·x[n][:] ----
    f4 accL[4][2];
#pragma unroll
    for (int i = 0; i < 4; ++i) { accL[i][0] = fz; accL[i][1] = fz; }
#pragma unroll
    for (int ks = 0; ks < 8; ++ks) {
      short8 xb[2], wl[4];
#pragma unroll
      for (int nj = 0; nj < 2; ++nj)
        xb[nj] = *(const short8*)(xlds + (32 * half + 16 * nj + l15) * XS + 32 * ks + 8 * q);
#pragma unroll
      for (int gi = 0; gi < 4; ++gi)
        wl[gi] = *(const short8*)(weff + (size_t)(h * 64 + 16 * gi + l15) * K_DIM + 32 * ks + 8 * q);
#pragma unroll
      for (int gi = 0; gi < 4; ++gi)
#pragma unroll
        for (int nj = 0; nj < 2; ++nj)
          accL[gi][nj] = MFMA(wl[gi], xb[nj], accL[gi][nj]);
    }
    // bias + temperature (beff loaded transiently; keeps persistent regs low)
#pragma unroll
    for (int gi = 0; gi < 4; ++gi) {
      f4 bv = *(const f4*)(beff + h * 64 + 16 * gi + 4 * q);
#pragma unroll
      for (int nj = 0; nj < 2; ++nj)
        accL[gi][nj] = (accL[gi][nj] + bv) * inv_t;
    }

    // ---- softmax over g; write sw^T bf16 directly into shared buf2 ----
#pragma unroll
    for (int nj = 0; nj < 2; ++nj) {
      float m = -3.0e38f;
#pragma unroll
      for (int gi = 0; gi < 4; ++gi)
#pragma unroll
        for (int r = 0; r < 4; ++r) m = fmaxf(m, accL[gi][nj][r]);
      m = fmaxf(m, __shfl_xor(m, 16));
      m = fmaxf(m, __shfl_xor(m, 32));
      float s = 0.f;
#pragma unroll
      for (int gi = 0; gi < 4; ++gi) {
        f4 e;
#pragma unroll
        for (int r = 0; r < 4; ++r) e[r] = __expf(accL[gi][nj][r] - m);
        accL[gi][nj] = e;
        s += e[0] + e[1] + e[2] + e[3];
      }
      s += __shfl_xor(s, 16);
      s += __shfl_xor(s, 32);
      const float rinv = 1.0f / s;
#pragma unroll
      for (int gi = 0; gi < 4; ++gi) {
        accL[gi][nj] *= rinv;
        snacc[gi] += accL[gi][nj];
#pragma unroll
        for (int r = 0; r < 4; ++r)
          buf2[(16 * gi + 4 * q + r) * PH_STR + 32 * half + 16 * nj + l15] =
              f2bf(accL[gi][nj][r]);
      }
    }

    // ---- fx GEMM for this wave's c-half: D[n][c] = x[n][:]·Wfx[c][:] ----
    f4 accF[4][2];
#pragma unroll
    for (int i = 0; i < 4; ++i) { accF[i][0] = fz; accF[i][1] = fz; }
#pragma unroll
    for (int ks = 0; ks < 8; ++ks) {
      short8 xa[4], wb[2];
#pragma unroll
      for (int mi = 0; mi < 4; ++mi)
        xa[mi] = *(const short8*)(xlds + (16 * mi + l15) * XS + 32 * ks + 8 * q);
#pragma unroll
      for (int cj = 0; cj < 2; ++cj)
        wb[cj] = *(const short8*)(wfx + (size_t)(h * 64 + 32 * half + 16 * cj + l15) * K_DIM +
                                  32 * ks + 8 * q);
#pragma unroll
      for (int mi = 0; mi < 4; ++mi)
#pragma unroll
        for (int cj = 0; cj < 2; ++cj)
          accF[mi][cj] = MFMA(xa[mi], wb[cj], accF[mi][cj]);
    }
    // flush fx^T[c][n] (own c-rows; bias loaded transiently)
#pragma unroll
    for (int cj = 0; cj < 2; ++cj) {
      const float bfv = bfx[h * 64 + 32 * half + 16 * cj + l15];
#pragma unroll
      for (int mi = 0; mi < 4; ++mi) {
        f4 v = accF[mi][cj] + bfv;
        *(us4*)(bufA + (32 * half + 16 * cj + l15) * PH_STR + 16 * mi + 4 * q) = pack4(v);
      }
    }
    __syncthreads();   // wave pair: sw^T + fx^T complete before pooling

    // ---- pooling: stacc[g][c-half] += sum_n sw^T[g][n] * fx^T[c][n] ----
#pragma unroll
    for (int kh = 0; kh < 2; ++kh) {
      short8 aw[4], bw[2];
#pragma unroll
      for (int mt = 0; mt < 4; ++mt)
        aw[mt] = *(const short8*)(buf2 + (16 * mt + l15) * PH_STR + 32 * kh + 8 * q);
#pragma unroll
      for (int ct = 0; ct < 2; ++ct)
        bw[ct] = *(const short8*)(bufA + (32 * half + 16 * ct + l15) * PH_STR + 32 * kh + 8 * q);
#pragma unroll
      for (int mt = 0; mt < 4; ++mt)
#pragma unroll
        for (int ct = 0; ct < 2; ++ct)
          stacc[mt][ct] = MFMA(aw[mt], bw[ct], stacc[mt][ct]);
    }
  }

  // ---- flush partials (own c-half columns of this head's slice) ----
  float* stp = part_st + (((size_t)bid * 4 + lh) << 12);
#pragma unroll
  for (int mt = 0; mt < 4; ++mt)
#pragma unroll
    for (int ct = 0; ct < 2; ++ct)
#pragma unroll
      for (int r = 0; r < 4; ++r)
        __builtin_nontemporal_store(
            stacc[mt][ct][r],
            stp + (16 * mt + 4 * q + r) * 64 + 32 * half + 16 * ct + l15);
  float* snp = part_sn + ((((size_t)bid * 4 + lh) * 2 + half) << 6);
#pragma unroll
  for (int gi = 0; gi < 4; ++gi)
#pragma unroll
    for (int r = 0; r < 4; ++r) {
      float vv = snacc[gi][r];
      vv += __shfl_xor(vv, 1);
      vv += __shfl_xor(vv, 2);
      vv += __shfl_xor(vv, 4);
      vv += __shfl_xor(vv, 8);
      if (l15 == 0) __builtin_nontemporal_store(vv, snp + 16 * gi + 4 * q + r);
    }
}

// ---------------- reduce: sum partials per (b,h) ----------------
// part_st slice for (b, ng, hg, lh) at ((b*128 + ng*2 + hg)*4 + lh)*4096.
__global__ void reduce_kernel(const float* __restrict__ part_st,
                              const float* __restrict__ part_sn,
                              float* __restrict__ stnum,
                              float* __restrict__ snorm) {
  const int gid = blockIdx.x * blockDim.x + threadIdx.x;  // [0, 131072)
  const int i = gid & 4095;
  const int h = (gid >> 12) & 7;
  const int b = gid >> 15;
  const float* p = part_st + ((size_t)(((b * 128) + (h >> 2)) * 4 + (h & 3)) << 12) + i;
  float s = 0.f;
#pragma unroll 8
  for (int ng = 0; ng < 64; ++ng)
    s += __builtin_nontemporal_load(p + (size_t)ng * (2 * 4 * 4096));
  stnum[(((size_t)b * 8 + h) << 12) + i] = s;
  if (gid < 2048) {
    const int g = gid & 63, h2 = (gid >> 6) & 7, b2 = gid >> 9;
    const float* ps = part_sn +
        ((size_t)((((b2 * 128) + (h2 >> 2)) * 4 + (h2 & 3)) * 2) << 6) + g;
    float s2 = 0.f;
#pragma unroll 8
    for (int ng = 0; ng < 64; ++ng) {
      s2 += __builtin_nontemporal_load(ps + (size_t)ng * 1024);
      s2 += __builtin_nontemporal_load(ps + (size_t)ng * 1024 + 64);
    }
    snorm[(((size_t)b2 * 8 + h2) << 6) + g] = s2;
  }
}

// ---------------- pass2: tiny slice-token attention (fp32) ----------------
__global__ void pass2_kernel(const float* __restrict__ stnum, const float* __restrict__ snorm,
                             const float* __restrict__ Wq, const float* __restrict__ Wk,
                             const float* __restrict__ Wv, const float* __restrict__ attn_scale,
                             const float* __restrict__ res_scale,
                             unsigned short* __restrict__ ostT) {
  extern __shared__ char lds2[];
  float* st = (float*)lds2;        // [64][65]
  float* kv = st + 64 * 65;        // reused as attn later
  float* kk = kv + 64 * 65;
  float* vv = kk + 64 * 65;
  float* qq = vv + 64 * 65;
  float* nk = qq + 64 * 65;        // [64]
  float* nq = nk + 64;             // [64]
  const int b = blockIdx.x >> 3, h = blockIdx.x & 7;
  const int tid = threadIdx.x;

  float kvr[16], str[16];
#pragma unroll
  for (int j = 0; j < 16; ++j) kvr[j] = 0.f;
  for (int h2 = 0; h2 < 8; ++h2) {
    const float* np = stnum + ((size_t)b * 8 + h2) * 4096;
    const float* sp = snorm + ((size_t)b * 8 + h2) * 64;
#pragma unroll
    for (int j = 0; j < 16; ++j) {
      int idx = tid + 256 * j;
      int g = idx >> 6;
      float v = np[idx] / (sp[g] + 1e-5f);
      kvr[j] += v;
      if (h2 == h) str[j] = v;
    }
  }
#pragma unroll
  for (int j = 0; j < 16; ++j) {
    int idx = tid + 256 * j;
    int g = idx >> 6, d = idx & 63;
    st[g * 65 + d] = str[j];
    kv[g * 65 + d] = kvr[j] * 0.125f;
  }
  __syncthreads();
#pragma unroll 2
  for (int j = 0; j < 16; ++j) {
    int idx = tid + 256 * j;
    int g = idx >> 6, dp = idx & 63;
    float a1 = 0, a2 = 0, a3 = 0;
    for (int dd = 0; dd < 64; ++dd) {
      float kvv = kv[g * 65 + dd], stv = st[g * 65 + dd];
      a1 += kvv * Wk[dp * 64 + dd];
      a2 += kvv * Wv[dp * 64 + dd];
      a3 += stv * Wq[dp * 64 + dd];
    }
    kk[g * 65 + dp] = a1;
    vv[g * 65 + dp] = a2;
    qq[g * 65 + dp] = a3;
  }
  __syncthreads();
  if (tid < 128) {
    int g = tid & 63;
    const float* p = (tid >= 64) ? qq : kk;
    float s = 0;
    for (int d = 0; d < 64; ++d) { float v = p[g * 65 + d]; s += v * v; }
    float nrm = fmaxf(sqrtf(s), 1e-12f);
    ((tid >= 64) ? nq : nk)[g] = nrm;
  }
  __syncthreads();
  const float scale = attn_scale[h];
  float* at = kv;  // reuse
#pragma unroll 2
  for (int j = 0; j < 16; ++j) {
    int idx = tid + 256 * j;
    int g = idx >> 6, s2 = idx & 63;
    float a = 0;
    for (int d = 0; d < 64; ++d) a += qq[g * 65 + d] * kk[s2 * 65 + d];
    at[g * 65 + s2] = a * scale / (nq[g] * nk[s2]);
  }
  __syncthreads();
  if (tid < 64) {
    int g = tid;
    float m = -3.0e38f;
    for (int s2 = 0; s2 < 64; ++s2) m = fmaxf(m, at[g * 65 + s2]);
    float ssum = 0;
    for (int s2 = 0; s2 < 64; ++s2) {
      float e = __expf(at[g * 65 + s2] - m);
      at[g * 65 + s2] = e;
      ssum += e;
    }
    float r = 1.f / ssum;
    for (int s2 = 0; s2 < 64; ++s2) at[g * 65 + s2] *= r;
  }
  __syncthreads();
  const float rs = res_scale[0];
#pragma unroll 2
  for (int j = 0; j < 16; ++j) {
    int idx = tid + 256 * j;
    int g = idx >> 6, d = idx & 63;
    float o = 0;
    for (int s2 = 0; s2 < 64; ++s2) o += at[g * 65 + s2] * vv[s2 * 65 + d];
    o += rs * st[g * 65 + d];
    ostT[(((size_t)b * 8 + h) * 64 + d) * 64 + g] = f2bf(o);  // transposed [d][g]
  }
}

// ---------------- pass3: recompute sw (direct Weff), scatter, final GEMM ----------------
// LDS ALIASING: ox (66.6 KB) reuses the xlds+buf region (74.75 KB) — xlds is dead
// after the logits GEMM, buf after the scatter MFMAs. One extra barrier guards the
// overwrite. LDS 141 KB -> 74.75 KB => 2 blocks/CU (16 waves) instead of 1: a
// co-resident block fills this block's barrier stalls.
__launch_bounds__(512, 1)
__global__ void pass3_kernel(const float* __restrict__ x,
                             const unsigned short* __restrict__ weff,
                             const unsigned short* __restrict__ wout,
                             const unsigned short* __restrict__ ostT,
                             const float* __restrict__ beff,
                             const float* __restrict__ temp,
                             const float* __restrict__ bout,
                             float* __restrict__ out) {
  extern __shared__ char lds[];
  const int tid = threadIdx.x;
  const int lane = tid & 63;
  const int h = tid >> 6;
  const int l15 = lane & 15;
  const int q = lane >> 4;
  const int b = blockIdx.x >> 9;          // 512 blocks per batch
  const int n0 = (blockIdx.x & 511) * 64;

  unsigned short* xlds = (unsigned short*)lds;
  unsigned short* buf = (unsigned short*)(lds + XLDS_BYTES + h * BUF2_BYTES);
  unsigned short* ox = (unsigned short*)lds;   // ALIASES xlds+buf (live ranges disjoint)

  const float inv_t = 1.0f / temp[h];
  f4 botg[4];
#pragma unroll
  for (int gi = 0; gi < 4; ++gi)
#pragma unroll
    for (int r = 0; r < 4; ++r) botg[gi][r] = beff[h * 64 + 16 * gi + 4 * q + r] * inv_t;
  float bout_v[2];
#pragma unroll
  for (int nt = 0; nt < 2; ++nt) bout_v[nt] = bout[32 * h + 16 * nt + l15];

  const float* xp = x + ((size_t)b * K_N + n0) * K_DIM;
  stage_x(xp, xlds, tid);
  __syncthreads();

  const f4 fz = {0.f, 0.f, 0.f, 0.f};
  // ---- logits GEMM (direct Weff) ----
  f4 accL[4][4];
#pragma unroll
  for (int i = 0; i < 4; ++i)
#pragma unroll
    for (int j = 0; j < 4; ++j) accL[i][j] = fz;
#pragma unroll
  for (int ks = 0; ks < 8; ++ks) {
    short8 xb[4], wl[4];
#pragma unroll
    for (int ni = 0; ni < 4; ++ni)
      xb[ni] = *(const short8*)(xlds + (16 * ni + l15) * XS + 32 * ks + 8 * q);
#pragma unroll
    for (int gi = 0; gi < 4; ++gi)
      wl[gi] = *(const short8*)(weff + (size_t)(h * 64 + 16 * gi + l15) * K_DIM + 32 * ks + 8 * q);
#pragma unroll
    for (int gi = 0; gi < 4; ++gi)
#pragma unroll
      for (int ni = 0; ni < 4; ++ni)
        accL[gi][ni] = MFMA(wl[gi], xb[ni], accL[gi][ni]);
  }
#pragma unroll
  for (int gi = 0; gi < 4; ++gi)
#pragma unroll
    for (int ni = 0; ni < 4; ++ni)
      accL[gi][ni] = accL[gi][ni] * inv_t + botg[gi];
  // ---- softmax over g ----
#pragma unroll
  for (int ni = 0; ni < 4; ++ni) {
    float m = -3.0e38f;
#pragma unroll
    for (int gi = 0; gi < 4; ++gi)
#pragma unroll
      for (int r = 0; r < 4; ++r) m = fmaxf(m, accL[gi][ni][r]);
    m = fmaxf(m, __shfl_xor(m, 16));
    m = fmaxf(m, __shfl_xor(m, 32));
    float s = 0.f;
#pragma unroll
    for (int gi = 0; gi < 4; ++gi) {
      f4 e;
#pragma unroll
      for (int r = 0; r < 4; ++r) e[r] = __expf(accL[gi][ni][r] - m);
      accL[gi][ni] = e;
      s += e[0] + e[1] + e[2] + e[3];
    }
    s += __shfl_xor(s, 16);
    s += __shfl_xor(s, 32);
    const float rinv = 1.0f / s;
#pragma unroll
    for (int gi = 0; gi < 4; ++gi) accL[gi][ni] *= rinv;
  }
  // ---- scatter: D[d][n] = sum_g ost^T[d][g] * sw[n][g] ----
  f4 accO[4][4];
#pragma unroll
  for (int i = 0; i < 4; ++i)
#pragma unroll
    for (int j = 0; j < 4; ++j) accO[i][j] = fz;
  const unsigned short* op = ostT + ((size_t)b * 8 + h) * 4096;
#pragma unroll
  for (int kh = 0; kh < 2; ++kh) {
#pragma unroll
    for (int gg = 0; gg < 2; ++gg) {
      const int gi = 2 * kh + gg;
#pragma unroll
      for (int ni = 0; ni < 4; ++ni)
        *(us4*)(buf + (16 * ni + l15) * BUF2_STR + 16 * gg + 4 * q) = pack4(accL[gi][ni]);
    }
    short8 ao[4], bo[4];
#pragma unroll
    for (int mt = 0; mt < 4; ++mt)
      ao[mt] = *(const short8*)(op + (16 * mt + l15) * 64 + 32 * kh + 8 * q);
#pragma unroll
    for (int ni = 0; ni < 4; ++ni)
      bo[ni] = *(const short8*)(buf + (16 * ni + l15) * BUF2_STR + 8 * q);
#pragma unroll
    for (int mt = 0; mt < 4; ++mt)
#pragma unroll
      for (int ni = 0; ni < 4; ++ni)
        accO[mt][ni] = MFMA(ao[mt], bo[ni], accO[mt][ni]);
  }
  __syncthreads();   // all waves done reading xlds/buf before ox overwrites them
#pragma unroll
  for (int mi = 0; mi < 4; ++mi)
#pragma unroll
    for (int ni = 0; ni < 4; ++ni)
      *(us4*)(ox + (16 * ni + l15) * OX_STR + h * 64 + 16 * mi + 4 * q) = pack4(accO[mi][ni]);
  __syncthreads();

  // ---- final GEMM: out = ox·Wout^T + bout ----
  f4 accC[4][2];
#pragma unroll
  for (int i = 0; i < 4; ++i)
#pragma unroll
    for (int j = 0; j < 2; ++j) accC[i][j] = fz;
#pragma unroll
  for (int ks = 0; ks < 16; ++ks) {
    short8 ax[4], bw8[2];
#pragma unroll
    for (int mt = 0; mt < 4; ++mt)
      ax[mt] = *(const short8*)(ox + (16 * mt + l15) * OX_STR + 32 * ks + 8 * q);
#pragma unroll
    for (int nt = 0; nt < 2; ++nt)
      bw8[nt] = *(const short8*)(wout + (size_t)(32 * h + 16 * nt + l15) * 512 + 32 * ks + 8 * q);
#pragma unroll
    for (int mt = 0; mt < 4; ++mt)
#pragma unroll
      for (int nt = 0; nt < 2; ++nt)
        accC[mt][nt] = MFMA(ax[mt], bw8[nt], accC[mt][nt]);
  }
  float* op2 = out + ((size_t)b * K_N + n0) * K_DIM;
#pragma unroll
  for (int mt = 0; mt < 4; ++mt)
#pragma unroll
    for (int nt = 0; nt < 2; ++nt) {
      f4 v = accC[mt][nt] + bout_v[nt];
#pragma unroll
      for (int r = 0; r < 4; ++r)
        __builtin_nontemporal_store(
            v[r], op2 + (size_t)(16 * mt + 4 * q + r) * K_DIM + 32 * h + 16 * nt + l15);
    }
}

// ---------------- host launch ----------------
extern "C" void kernel_launch(void* const* d_in, const int* in_sizes, int n_in,
                              void* d_out, int out_size, void* d_ws, size_t ws_size,
                              hipStream_t stream) {
  const float* x    = (const float*)d_in[0];
  const float* Wfx  = (const float*)d_in[1];
  const float* bfx  = (const float*)d_in[2];
  const float* Wx   = (const float*)d_in[3];
  const float* bx   = (const float*)d_in[4];
  const float* Wsl  = (const float*)d_in[5];
  const float* bsl  = (const float*)d_in[6];
  const float* temp = (const float*)d_in[7];
  const float* Wq   = (const float*)d_in[8];
  const float* Wk   = (const float*)d_in[9];
  const float* Wv   = (const float*)d_in[10];
  const float* rs   = (const float*)d_in[11];
  const float* asc  = (const float*)d_in[12];
  const float* Wout = (const float*)d_in[13];
  const float* bout = (const float*)d_in[14];
  float* out = (float*)d_out;
  char* ws = (char*)d_ws;

  unsigned short* wfxb  = (unsigned short*)(ws + WFX_OFF);
  unsigned short* weffb = (unsigned short*)(ws + WX_OFF);
  unsigned short* woutb = (unsigned short*)(ws + WOUT_OFF);
  const float* beffp    = (const float*)(ws + WSL_OFF);
  float* stn = (float*)(ws + STN_OFF);
  float* snr = (float*)(ws + SNORM_OFF);
  unsigned short* ostb = (unsigned short*)(ws + OST_OFF);
  // partial accumulators live in d_out (128 MiB); pass3 overwrites all of d_out later.
  float* pst = out;                    // 8388608 floats = 32 MiB
  float* psn = out + PART_ST_FLOATS;   // 262144 floats  = 1 MiB

  (void)hipFuncSetAttribute((const void*)pass1_kernel,
                            hipFuncAttributeMaxDynamicSharedMemorySize, P1_LDS);
  (void)hipFuncSetAttribute((const void*)pass2_kernel,
                            hipFuncAttributeMaxDynamicSharedMemorySize, P2_LDS);
  (void)hipFuncSetAttribute((const void*)pass3_kernel,
                            hipFuncAttributeMaxDynamicSharedMemorySize, P3_LDS);

  prep_kernel<<<256, 256, 0, stream>>>(Wfx, Wx, Wsl, Wout, bx, bsl, ws);
  pass1_kernel<<<512, 512, P1_LDS, stream>>>(x, wfxb, weffb, beffp, bfx, temp, pst, psn);
  reduce_kernel<<<512, 256, 0, stream>>>(pst, psn, stn, snr);
  pass2_kernel<<<32, 256, P2_LDS, stream>>>(stn, snr, Wq, Wk, Wv, asc, rs, ostb);
  pass3_kernel<<<2048, 512, P3_LDS, stream>>>(x, weffb, woutb, ostb, beffp, temp, bout, out);
}